// Round 9
// baseline (268.908 us; speedup 1.0000x reference)
//
#include <hip/hip_runtime.h>
#include <hip/hip_bf16.h>
#include <math.h>

// Problem constants
#define NB   2
#define LSEQ 384
#define DMODEL 512
#define NH   8
#define HD2  64
#define DMLP 2048
#define LL2  (LSEQ*LSEQ)          // 147456
#define ROWS (NB*LSEQ)            // 768

using bf16x8 = __attribute__((ext_vector_type(8))) short;
using f32x4  = __attribute__((ext_vector_type(4))) float;

__device__ __forceinline__ unsigned short f2bf(float f) {
    union { __hip_bfloat16 h; unsigned short u; } cv;
    cv.h = __float2bfloat16(f);
    return cv.u;
}
__device__ __forceinline__ float bf2f(unsigned short u) {
    union { float f; unsigned int i; } c;
    c.i = ((unsigned int)u) << 16;
    return c.f;
}

__device__ __forceinline__ void gload_lds16(const void* g, void* l) {
    __builtin_amdgcn_global_load_lds(
        (const __attribute__((address_space(1))) void*)g,
        (__attribute__((address_space(3))) void*)l, 16, 0, 0);
}

// ---------------------------------------------------------------------------
// pre: LN1(x)+LN1(mem) (blocks 0..383) + f32->bf16 weight conversions (rest)
__global__ __launch_bounds__(256) void pre_kernel(
        const float* __restrict__ x, const float* __restrict__ mem,
        const float* __restrict__ ln1g, const float* __restrict__ ln1b,
        unsigned short* __restrict__ a_in, unsigned short* __restrict__ a_mem,
        const float* __restrict__ s0, const float* __restrict__ s1,
        const float* __restrict__ s2, const float* __restrict__ s3,
        const float* __restrict__ s4, const float* __restrict__ s5,
        const float* __restrict__ edw,
        unsigned short* __restrict__ d0, unsigned short* __restrict__ d1,
        unsigned short* __restrict__ d2, unsigned short* __restrict__ d3,
        unsigned short* __restrict__ d4, unsigned short* __restrict__ d5,
        unsigned short* __restrict__ edwb) {
    const int tid = threadIdx.x;
    if (blockIdx.x < 384) {
        int lane = tid & 63;
        int row  = blockIdx.x * 4 + (tid >> 6);
        const float* src = (row < ROWS) ? x : mem;
        unsigned short* dst = (row < ROWS) ? a_in : a_mem;
        int r2 = (row < ROWS) ? row : row - ROWS;
        const float* p = src + (size_t)r2 * DMODEL + lane * 8;
        float4 v0 = *(const float4*)p;
        float4 v1 = *(const float4*)(p + 4);
        float s  = v0.x + v0.y + v0.z + v0.w + v1.x + v1.y + v1.z + v1.w;
        float ss = v0.x*v0.x + v0.y*v0.y + v0.z*v0.z + v0.w*v0.w
                 + v1.x*v1.x + v1.y*v1.y + v1.z*v1.z + v1.w*v1.w;
        #pragma unroll
        for (int o = 32; o; o >>= 1) { s += __shfl_xor(s, o); ss += __shfl_xor(ss, o); }
        float m   = s * (1.0f / DMODEL);
        float var = ss * (1.0f / DMODEL) - m * m;
        float r   = rsqrtf(var + 1e-5f);
        float4 g0 = *(const float4*)(ln1g + lane * 8);
        float4 g1 = *(const float4*)(ln1g + lane * 8 + 4);
        float4 b0 = *(const float4*)(ln1b + lane * 8);
        float4 b1 = *(const float4*)(ln1b + lane * 8 + 4);
        unsigned short* q = dst + (size_t)r2 * DMODEL + lane * 8;
        ushort4 lo = {f2bf((v0.x-m)*r*g0.x+b0.x), f2bf((v0.y-m)*r*g0.y+b0.y),
                      f2bf((v0.z-m)*r*g0.z+b0.z), f2bf((v0.w-m)*r*g0.w+b0.w)};
        ushort4 hi = {f2bf((v1.x-m)*r*g1.x+b1.x), f2bf((v1.y-m)*r*g1.y+b1.y),
                      f2bf((v1.z-m)*r*g1.z+b1.z), f2bf((v1.w-m)*r*g1.w+b1.w)};
        *(ushort4*)q = lo;
        *(ushort4*)(q + 4) = hi;
        return;
    }
    const int stride = (gridDim.x - 384) * 256;
    const int t0 = (blockIdx.x - 384) * 256 + tid;
    const float* srcs[6] = {s0, s1, s2, s3, s4, s5};
    unsigned short* dsts[6] = {d0, d1, d2, d3, d4, d5};
    const int nf4[6] = {DMODEL*DMODEL/4, 2*DMODEL*DMODEL/4, DMODEL*DMODEL/4,
                        DMLP*DMODEL/4, DMLP*DMLP/4, DMLP*DMODEL/4};
    #pragma unroll
    for (int a = 0; a < 6; a++) {
        const float* s = srcs[a];
        unsigned short* d = dsts[a];
        for (int i = t0; i < nf4[a]; i += stride) {
            float4 v = *(const float4*)(s + (size_t)i * 4);
            ushort4 o = {f2bf(v.x), f2bf(v.y), f2bf(v.z), f2bf(v.w)};
            *(ushort4*)(d + (size_t)i * 4) = o;
        }
    }
    for (int i = t0; i < 16 * 512 / 4; i += stride) {
        int row = i >> 7;
        float4 v = {0.f, 0.f, 0.f, 0.f};
        if (row < 8) v = *(const float4*)(edw + (size_t)i * 4);
        ushort4 o = {f2bf(v.x), f2bf(v.y), f2bf(v.z), f2bf(v.w)};
        *(ushort4*)(edwb + (size_t)i * 4) = o;
    }
}

// ---------------------------------------------------------------------------
// LayerNorm (ln2): one wave per row
__global__ __launch_bounds__(256) void ln_kernel(const float* __restrict__ src0,
                                                 const float* __restrict__ g,
                                                 const float* __restrict__ b,
                                                 unsigned short* __restrict__ dst0) {
    int lane = threadIdx.x & 63;
    int row  = blockIdx.x * 4 + (threadIdx.x >> 6);
    const float* p = src0 + (size_t)row * DMODEL + lane * 8;
    float4 v0 = *(const float4*)p;
    float4 v1 = *(const float4*)(p + 4);
    float s  = v0.x + v0.y + v0.z + v0.w + v1.x + v1.y + v1.z + v1.w;
    float ss = v0.x*v0.x + v0.y*v0.y + v0.z*v0.z + v0.w*v0.w
             + v1.x*v1.x + v1.y*v1.y + v1.z*v1.z + v1.w*v1.w;
    #pragma unroll
    for (int o = 32; o; o >>= 1) { s += __shfl_xor(s, o); ss += __shfl_xor(ss, o); }
    float m   = s * (1.0f / DMODEL);
    float var = ss * (1.0f / DMODEL) - m * m;
    float r   = rsqrtf(var + 1e-5f);
    float4 g0 = *(const float4*)(g + lane * 8);
    float4 g1 = *(const float4*)(g + lane * 8 + 4);
    float4 b0 = *(const float4*)(b + lane * 8);
    float4 b1 = *(const float4*)(b + lane * 8 + 4);
    unsigned short* q = dst0 + (size_t)row * DMODEL + lane * 8;
    ushort4 lo = {f2bf((v0.x-m)*r*g0.x+b0.x), f2bf((v0.y-m)*r*g0.y+b0.y),
                  f2bf((v0.z-m)*r*g0.z+b0.z), f2bf((v0.w-m)*r*g0.w+b0.w)};
    ushort4 hi = {f2bf((v1.x-m)*r*g1.x+b1.x), f2bf((v1.y-m)*r*g1.y+b1.y),
                  f2bf((v1.z-m)*r*g1.z+b1.z), f2bf((v1.w-m)*r*g1.w+b1.w)};
    *(ushort4*)q = lo;
    *(ushort4*)(q + 4) = hi;
}

// ---------------------------------------------------------------------------
// bias v5: R8 layout (32 KB LDS, 5 blocks/CU, bf16 out) but with counted
// vmcnt: wait vmcnt(4) keeps the next chunk's 4 loads in flight across the
// barrier; second barrier releases the buffer before restaging.
__global__ __launch_bounds__(256) void bias_mfma(const float* __restrict__ pd,
                                                 const unsigned short* __restrict__ edwb,
                                                 const float* __restrict__ edb,
                                                 const int* __restrict__ mask,
                                                 unsigned short* __restrict__ biasb) {
    __shared__ float Asb[2][64 * 64];    // 2 x 16KB
    const int tid = threadIdx.x;
    const int lane = tid & 63, w = tid >> 6;
    const int T = blockIdx.x;            // 4608 tiles of 64 ij
    const size_t row0 = (size_t)T * 64;
    const int n = T / 2304;
    const int rem64 = (T - n * 2304) * 64;
    const int i = rem64 / LSEQ, j0 = rem64 % LSEQ;

    const int c = lane & 15, g = lane >> 4;
    // preload edw fragments (16 x bf16x8)
    bf16x8 bfv[8][2];
    #pragma unroll
    for (int kc = 0; kc < 8; kc++)
        #pragma unroll
        for (int ks = 0; ks < 2; ks++)
            bfv[kc][ks] = *(const bf16x8*)&edwb[c * 512 + kc * 64 + ks * 32 + g * 8];

    // allpad for this n (in-wave)
    int pad = 1;
    for (int j = lane; j < LSEQ; j += 64) pad &= (mask[n * LSEQ + j] != 0) ? 1 : 0;
    unsigned long long bal = __ballot(pad);
    const int ap = (bal == ~0ull) ? 1 : 0;

    int rr[4], sc[4];
    #pragma unroll
    for (int q = 0; q < 4; q++) {
        int s = q * 256 + tid;
        rr[q] = s >> 4;
        int cs = s & 15;
        sc[q] = (cs & 8) | ((cs & 7) ^ (rr[q] & 7));
    }

    f32x4 acc = {};

    // stage chunk kc (4 loads/thread) into buf kc&1
    #define STAGEB(kc_) { const int b_ = ((kc_) & 1) * 4096;                          \
        _Pragma("unroll")                                                             \
        for (int q = 0; q < 4; q++)                                                   \
            gload_lds16(pd + (row0 + rr[q]) * DMODEL + (kc_) * 64 + sc[q] * 4,        \
                        &Asb[0][b_ + (q * 256 + tid) * 4]); }
    STAGEB(0); STAGEB(1);

    #pragma unroll
    for (int kc = 0; kc < 8; kc++) {
        if (kc < 7) asm volatile("s_waitcnt vmcnt(4)" ::: "memory");
        else        asm volatile("s_waitcnt vmcnt(0)" ::: "memory");
        __builtin_amdgcn_s_barrier();
        __builtin_amdgcn_sched_barrier(0);
        const float* Ab = &Asb[0][(kc & 1) * 4096];
        #pragma unroll
        for (int ks = 0; ks < 2; ks++) {
            const int ch0 = (8 * ks) | ((2 * g) ^ (c & 7));
            const int ch1 = (8 * ks) | ((2 * g + 1) ^ (c & 7));
            float4 a0 = *(const float4*)&Ab[(w * 16 + c) * 64 + ch0 * 4];
            float4 a1 = *(const float4*)&Ab[(w * 16 + c) * 64 + ch1 * 4];
            bf16x8 af;
            af[0] = (short)f2bf(a0.x); af[1] = (short)f2bf(a0.y);
            af[2] = (short)f2bf(a0.z); af[3] = (short)f2bf(a0.w);
            af[4] = (short)f2bf(a1.x); af[5] = (short)f2bf(a1.y);
            af[6] = (short)f2bf(a1.z); af[7] = (short)f2bf(a1.w);
            acc = __builtin_amdgcn_mfma_f32_16x16x32_bf16(af, bfv[kc][ks], acc, 0, 0, 0);
        }
        __builtin_amdgcn_sched_barrier(0);
        __builtin_amdgcn_s_barrier();   // buffer kc&1 free for restage
        if (kc + 2 < 8) STAGEB(kc + 2);
    }
    #undef STAGEB

    if (c < 8) {
        const float eb = edb[c];
        const int jj = j0 + w * 16 + g * 4;
        int4 mv = *(const int4*)&mask[n * LSEQ + jj];
        const float NEGINF = -__builtin_inff();
        ushort4 o;
        o.x = f2bf(acc[0] + eb + ((!ap && mv.x) ? NEGINF : 0.0f));
        o.y = f2bf(acc[1] + eb + ((!ap && mv.y) ? NEGINF : 0.0f));
        o.z = f2bf(acc[2] + eb + ((!ap && mv.z) ? NEGINF : 0.0f));
        o.w = f2bf(acc[3] + eb + ((!ap && mv.w) ? NEGINF : 0.0f));
        *(ushort4*)&biasb[(size_t)(n * 8 + c) * LL2 + (size_t)i * LSEQ + jj] = o;
    }
}

// ---------------------------------------------------------------------------
// bf16 MFMA GEMM body (R4-proven): 64x64 tile, 4 waves, BK=64, 4-deep
// pipelined staging (counted vmcnt + raw barriers), XOR-swizzled LDS.
template<int ACT, int RES, int OBF>
__device__ __forceinline__ void gemm_body(const unsigned short* __restrict__ A,
        const unsigned short* __restrict__ W, const float* __restrict__ bv,
        const float* __restrict__ Rsd, void* __restrict__ Cv,
        int Nn, int K, int m0, int n0, short* As, short* Ws) {
    const int tid  = threadIdx.x;
    const int lane = tid & 63, w = tid >> 6;
    const int wr = w >> 1, wc = w & 1;
    const int s0 = tid, s1 = 256 + tid;
    const int r0 = s0 >> 3, c0 = ((s0 & 7) ^ (r0 & 7)) << 3;
    const int r1 = s1 >> 3, c1 = ((s1 & 7) ^ (r1 & 7)) << 3;
    const unsigned short* ag0 = A + (size_t)(m0 + r0) * K + c0;
    const unsigned short* ag1 = A + (size_t)(m0 + r1) * K + c1;
    const unsigned short* wg0 = W + (size_t)(n0 + r0) * K + c0;
    const unsigned short* wg1 = W + (size_t)(n0 + r1) * K + c1;

    f32x4 acc[2][2] = {};
    const int lc = lane & 15, lr = lane >> 4;
    const int KT = K >> 6;

    #pragma unroll
    for (int t = 0; t < 4; t++) {
        const int b = t * 4096, k0 = t << 6;
        gload_lds16(ag0 + k0, &As[b + s0 * 8]);
        gload_lds16(ag1 + k0, &As[b + s1 * 8]);
        gload_lds16(wg0 + k0, &Ws[b + s0 * 8]);
        gload_lds16(wg1 + k0, &Ws[b + s1 * 8]);
    }

    for (int t = 0; t < KT; t++) {
        int rem = KT - 1 - t; if (rem > 3) rem = 3;
        if (rem >= 3)      asm volatile("s_waitcnt vmcnt(12)" ::: "memory");
        else if (rem == 2) asm volatile("s_waitcnt vmcnt(8)"  ::: "memory");
        else if (rem == 1) asm volatile("s_waitcnt vmcnt(4)"  ::: "memory");
        else               asm volatile("s_waitcnt vmcnt(0)"  ::: "memory");
        __builtin_amdgcn_s_barrier();
        __builtin_amdgcn_sched_barrier(0);
        const int cur = (t & 3) * 4096;
        bf16x8 af[2][2], bfr[2][2];
        #pragma unroll
        for (int m = 0; m < 2; m++) {
            const int rra = wr * 32 + m * 16 + lc;
            #pragma unroll
            for (int kk = 0; kk < 2; kk++) {
                const int cc = (lr + kk * 4) ^ (rra & 7);
                af[m][kk] = *(const bf16x8*)&As[cur + rra * 64 + cc * 8];
            }
        }
        #pragma unroll
        for (int nn = 0; nn < 2; nn++) {
            const int rrb = wc * 32 + nn * 16 + lc;
            #pragma unroll
            for (int kk = 0; kk < 2; kk++) {
                const int cc = (lr + kk * 4) ^ (rrb & 7);
                bfr[nn][kk] = *(const bf16x8*)&Ws[cur + rrb * 64 + cc * 8];
            }
        }
        #pragma unroll
        for (int m = 0; m < 2; m++)
            #pragma unroll
            for (int nn = 0; nn < 2; nn++) {
                acc[m][nn] = __builtin_amdgcn_mfma_f32_16x16x32_bf16(af[m][0], bfr[nn][0], acc[m][nn], 0, 0, 0);
                acc[m][nn] = __builtin_amdgcn_mfma_f32_16x16x32_bf16(af[m][1], bfr[nn][1], acc[m][nn], 0, 0, 0);
            }
        if (t + 4 < KT) {
            __builtin_amdgcn_sched_barrier(0);
            __builtin_amdgcn_s_barrier();
            const int b = cur, k0 = (t + 4) << 6;
            gload_lds16(ag0 + k0, &As[b + s0 * 8]);
            gload_lds16(ag1 + k0, &As[b + s1 * 8]);
            gload_lds16(wg0 + k0, &Ws[b + s0 * 8]);
            gload_lds16(wg1 + k0, &Ws[b + s1 * 8]);
        }
    }

    #pragma unroll
    for (int nn = 0; nn < 2; nn++) {
        int gcol = n0 + wc * 32 + nn * 16 + lc;
        float bb = bv[gcol];
        #pragma unroll
        for (int m = 0; m < 2; m++) {
            #pragma unroll
            for (int r = 0; r < 4; r++) {
                int grow = m0 + wr * 32 + m * 16 + lr * 4 + r;
                float o = acc[m][nn][r] + bb;
                if (ACT) o = o / (1.0f + expf(-o));
                if (RES) o += Rsd[(size_t)grow * Nn + gcol];
                if (OBF) ((unsigned short*)Cv)[(size_t)grow * Nn + gcol] = f2bf(o);
                else     ((float*)Cv)[(size_t)grow * Nn + gcol] = o;
            }
        }
    }
}

template<int ACT, int RES, int OBF>
__global__ __launch_bounds__(256) void mfma_gemm(const unsigned short* __restrict__ A,
                                                 const unsigned short* __restrict__ W,
                                                 const float* __restrict__ bv,
                                                 const float* __restrict__ Rsd,
                                                 void* __restrict__ Cv, int Nn, int K) {
    __shared__ short As[4 * 4096];
    __shared__ short Ws[4 * 4096];
    gemm_body<ACT, RES, OBF>(A, W, bv, Rsd, Cv, Nn, K, blockIdx.y * 64, blockIdx.x * 64, As, Ws);
}

// merged q + kv projection
__global__ __launch_bounds__(256) void qkv_gemm(const unsigned short* __restrict__ a_in,
                                                const unsigned short* __restrict__ a_mem,
                                                const unsigned short* __restrict__ qwb,
                                                const unsigned short* __restrict__ kvwb,
                                                const float* __restrict__ qbv,
                                                const float* __restrict__ kvbv,
                                                float* __restrict__ qbuf,
                                                float* __restrict__ kvbuf) {
    __shared__ short As[4 * 4096];
    __shared__ short Ws[4 * 4096];
    const int bx = blockIdx.x;
    const unsigned short* A; const unsigned short* W; const float* bv; float* C; int Nn, n0;
    if (bx < 8) { A = a_in;  W = qwb;  bv = qbv;  C = qbuf;  Nn = DMODEL;     n0 = bx * 64; }
    else        { A = a_mem; W = kvwb; bv = kvbv; C = kvbuf; Nn = 2 * DMODEL; n0 = (bx - 8) * 64; }
    gemm_body<0, 0, 0>(A, W, bv, nullptr, C, Nn, DMODEL, blockIdx.y * 64, n0, As, Ws);
}

// ---------------------------------------------------------------------------
// scores[n,h,i,j] = 0.125 * q_i.k_j + bf2f(biasb[n,h,i,j])  (mask pre-folded)
__global__ __launch_bounds__(256) void scores_kernel(const float* __restrict__ q,
                                                     const float* __restrict__ kv,
                                                     const unsigned short* __restrict__ biasb,
                                                     float* __restrict__ S) {
    const int n = blockIdx.z, h = blockIdx.y;
    const int it = blockIdx.x / 12, jt = blockIdx.x % 12;
    __shared__ float Qs[64][32];
    __shared__ float Ks[64][32];
    const int tid = threadIdx.x;
    const int r = tid >> 3, c = (tid & 7) << 3;
    {
        const float* qp = q + ((size_t)(n * LSEQ + it * 32 + r)) * DMODEL + h * HD2 + c;
        float4 q0 = *(const float4*)qp;
        float4 q1 = *(const float4*)(qp + 4);
        Qs[c+0][r]=q0.x; Qs[c+1][r]=q0.y; Qs[c+2][r]=q0.z; Qs[c+3][r]=q0.w;
        Qs[c+4][r]=q1.x; Qs[c+5][r]=q1.y; Qs[c+6][r]=q1.z; Qs[c+7][r]=q1.w;
        const float* kp = kv + ((size_t)(n * LSEQ + jt * 32 + r)) * (2 * DMODEL) + h * HD2 + c;
        float4 k0 = *(const float4*)kp;
        float4 k1 = *(const float4*)(kp + 4);
        Ks[c+0][r]=k0.x; Ks[c+1][r]=k0.y; Ks[c+2][r]=k0.z; Ks[c+3][r]=k0.w;
        Ks[c+4][r]=k1.x; Ks[c+5][r]=k1.y; Ks[c+6][r]=k1.z; Ks[c+7][r]=k1.w;
    }
    __syncthreads();
    const int tx = tid & 15, ty = tid >> 4;
    float acc[2][2] = {{0.f,0.f},{0.f,0.f}};
    #pragma unroll
    for (int k = 0; k < 64; k++) {
        float2 a  = *(const float2*)&Qs[k][ty << 1];
        float2 b2 = *(const float2*)&Ks[k][tx << 1];
        acc[0][0] = fmaf(a.x, b2.x, acc[0][0]);
        acc[0][1] = fmaf(a.x, b2.y, acc[0][1]);
        acc[1][0] = fmaf(a.y, b2.x, acc[1][0]);
        acc[1][1] = fmaf(a.y, b2.y, acc[1][1]);
    }
    #pragma unroll
    for (int i2 = 0; i2 < 2; i2++) {
        int gi = it * 32 + (ty << 1) + i2;
        int gj = jt * 32 + (tx << 1);
        size_t idx = ((size_t)(n * 8 + h)) * LL2 + (size_t)gi * LSEQ + gj;
        ushort2 bb = *(const ushort2*)&biasb[idx];
        S[idx]     = acc[i2][0] * 0.125f + bf2f(bb.x);
        S[idx + 1] = acc[i2][1] * 0.125f + bf2f(bb.y);
    }
}

// ---------------------------------------------------------------------------
// row softmax over 384 cols; one wave per row
__global__ __launch_bounds__(256) void softmax_kernel(float* __restrict__ S) {
    int lane = threadIdx.x & 63;
    int row  = blockIdx.x * 4 + (threadIdx.x >> 6);
    float* p = S + (size_t)row * LSEQ;
    float v[6];
    #pragma unroll
    for (int cc = 0; cc < 6; cc++) v[cc] = p[cc * 64 + lane];
    float mx = v[0];
    #pragma unroll
    for (int cc = 1; cc < 6; cc++) mx = fmaxf(mx, v[cc]);
    #pragma unroll
    for (int o = 32; o; o >>= 1) mx = fmaxf(mx, __shfl_xor(mx, o));
    float sum = 0.f;
    #pragma unroll
    for (int cc = 0; cc < 6; cc++) { v[cc] = __expf(v[cc] - mx); sum += v[cc]; }
    #pragma unroll
    for (int o = 32; o; o >>= 1) sum += __shfl_xor(sum, o);
    float inv = 1.0f / sum;
    #pragma unroll
    for (int cc = 0; cc < 6; cc++) p[cc * 64 + lane] = v[cc] * inv;
}

// ---------------------------------------------------------------------------
// attn_out = P @ V  -> bf16; allpad computed in-wave
__global__ __launch_bounds__(256) void av_kernel(const float* __restrict__ S,
                                                 const float* __restrict__ kv,
                                                 const int* __restrict__ mask,
                                                 unsigned short* __restrict__ outb) {
    const int it = blockIdx.x, h = blockIdx.y, n = blockIdx.z;
    __shared__ float Ps[32][68];
    __shared__ float Vs[64][68];
    const int tid = threadIdx.x;
    const int lane = tid & 63;
    int pad = 1;
    for (int j = lane; j < LSEQ; j += 64) pad &= (mask[n * LSEQ + j] != 0) ? 1 : 0;
    unsigned long long bal = __ballot(pad != 0);
    const float zf = (bal == 0xFFFFFFFFFFFFFFFFull) ? 0.0f : 1.0f;
    const int tx = tid & 15, ty = tid >> 4;
    const int pr = tid >> 3, pc = (tid & 7) << 3;
    const int vr = tid >> 2, vc = (tid & 3) << 4;
    float acc0[4] = {0,0,0,0}, acc1[4] = {0,0,0,0};
    for (int j0 = 0; j0 < LSEQ; j0 += 64) {
        const float* sp = S + ((size_t)(n * 8 + h)) * LL2 + (size_t)(it * 32 + pr) * LSEQ + j0 + pc;
        float4 p0 = *(const float4*)sp;
        float4 p1 = *(const float4*)(sp + 4);
        *(float4*)&Ps[pr][pc]     = p0;
        *(float4*)&Ps[pr][pc + 4] = p1;
        #pragma unroll
        for (int u = 0; u < 4; u++) {
            float4 vvv = *(const float4*)&kv[((size_t)(n * LSEQ + j0 + vr)) * (2 * DMODEL)
                                             + DMODEL + h * HD2 + vc + 4 * u];
            *(float4*)&Vs[vr][vc + 4 * u] = vvv;
        }
        __syncthreads();
        #pragma unroll
        for (int j = 0; j < 64; j++) {
            float pa  = Ps[ty][j];
            float pb2 = Ps[ty + 16][j];
            float4 vv = *(const float4*)&Vs[j][tx << 2];
            acc0[0] = fmaf(pa,  vv.x, acc0[0]);
            acc0[1] = fmaf(pa,  vv.y, acc0[1]);
            acc0[2] = fmaf(pa,  vv.z, acc0[2]);
            acc0[3] = fmaf(pa,  vv.w, acc0[3]);
            acc1[0] = fmaf(pb2, vv.x, acc1[0]);
            acc1[1] = fmaf(pb2, vv.y, acc1[1]);
            acc1[2] = fmaf(pb2, vv.z, acc1[2]);
            acc1[3] = fmaf(pb2, vv.w, acc1[3]);
        }
        __syncthreads();
    }
    int i0 = it * 32;
    ushort4 o0 = {f2bf(acc0[0]*zf), f2bf(acc0[1]*zf), f2bf(acc0[2]*zf), f2bf(acc0[3]*zf)};
    ushort4 o1 = {f2bf(acc1[0]*zf), f2bf(acc1[1]*zf), f2bf(acc1[2]*zf), f2bf(acc1[3]*zf)};
    *(ushort4*)&outb[((size_t)(n * LSEQ + i0 + ty)) * DMODEL + h * HD2 + (tx << 2)]      = o0;
    *(ushort4*)&outb[((size_t)(n * LSEQ + i0 + ty + 16)) * DMODEL + h * HD2 + (tx << 2)] = o1;
}

// ---------------------------------------------------------------------------
extern "C" void kernel_launch(void* const* d_in, const int* in_sizes, int n_in,
                              void* d_out, int out_size, void* d_ws, size_t ws_size,
                              hipStream_t stream) {
    const float* x    = (const float*)d_in[0];
    const float* mem  = (const float*)d_in[1];
    const float* pd   = (const float*)d_in[2];
    const int*   mask = (const int*)d_in[3];
    const float* qw   = (const float*)d_in[4];
    const float* qbv  = (const float*)d_in[5];
    const float* kvw  = (const float*)d_in[6];
    const float* kvbv = (const float*)d_in[7];
    const float* pw   = (const float*)d_in[8];
    const float* pbv  = (const float*)d_in[9];
    const float* edw  = (const float*)d_in[10];
    const float* edb  = (const float*)d_in[11];
    const float* ln1g = (const float*)d_in[12];
    const float* ln1b = (const float*)d_in[13];
    const float* ln2g = (const float*)d_in[14];
    const float* ln2b = (const float*)d_in[15];
    const float* w1   = (const float*)d_in[16];
    const float* b1   = (const float*)d_in[17];
    const float* w2   = (const float*)d_in[18];
    const float* b2   = (const float*)d_in[19];
    const float* w3   = (const float*)d_in[20];
    const float* b3   = (const float*)d_in[21];

    float* wsf = (float*)d_ws;
    unsigned short* biasb = (unsigned short*)(wsf + 16);     // NB*NH*LL2 bf16
    float* scores = wsf + 16 + (size_t)NB * NH * LL2 / 2;    // f32
    float* qbuf   = scores + (size_t)NB * NH * LL2;
    float* kvbuf  = qbuf + (size_t)ROWS * DMODEL;
    float* x1buf  = kvbuf + (size_t)ROWS * 2 * DMODEL;
    unsigned short* a_in  = (unsigned short*)(x1buf + (size_t)ROWS * DMODEL);
    unsigned short* a_mem = a_in  + (size_t)ROWS * DMODEL;
    unsigned short* attno = a_mem + (size_t)ROWS * DMODEL;
    unsigned short* h0    = attno + (size_t)ROWS * DMODEL;
    unsigned short* h1    = h0    + (size_t)ROWS * DMODEL;
    unsigned short* h2    = h1    + (size_t)ROWS * DMLP;
    unsigned short* qwb   = h2    + (size_t)ROWS * DMLP;
    unsigned short* kvwb  = qwb   + (size_t)DMODEL * DMODEL;
    unsigned short* pwb   = kvwb  + (size_t)2 * DMODEL * DMODEL;
    unsigned short* w1b   = pwb   + (size_t)DMODEL * DMODEL;
    unsigned short* w2b   = w1b   + (size_t)DMLP * DMODEL;
    unsigned short* w3b   = w2b   + (size_t)DMLP * DMLP;
    unsigned short* edwb  = w3b   + (size_t)DMLP * DMODEL;   // 16*512 bf16

    float* outp = (float*)d_out;

    pre_kernel<<<2048, 256, 0, stream>>>(x, mem, ln1g, ln1b, a_in, a_mem,
                                         qw, kvw, pw, w1, w2, w3, edw,
                                         qwb, kvwb, pwb, w1b, w2b, w3b, edwb);
    bias_mfma<<<NB * LL2 / 64, 256, 0, stream>>>(pd, edwb, edb, mask, biasb);
    qkv_gemm<<<dim3(24, 12), 256, 0, stream>>>(a_in, a_mem, qwb, kvwb, qbv, kvbv, qbuf, kvbuf);

    scores_kernel<<<dim3(144, NH, NB), 256, 0, stream>>>(qbuf, kvbuf, biasb, scores);
    softmax_kernel<<<(NB * NH * LSEQ) / 4, 256, 0, stream>>>(scores);
    av_kernel<<<dim3(12, NH, NB), 256, 0, stream>>>(scores, kvbuf, mask, attno);

    mfma_gemm<0,1,0><<<dim3(8, 12), 256, 0, stream>>>(attno, pwb, pbv, x, x1buf, DMODEL, DMODEL);
    ln_kernel<<<ROWS / 4, 256, 0, stream>>>(x1buf, ln2g, ln2b, h0);
    mfma_gemm<1,0,1><<<dim3(32, 12), 256, 0, stream>>>(h0, w1b, b1, nullptr, h1, DMLP, DMODEL);
    mfma_gemm<1,0,1><<<dim3(32, 12), 256, 0, stream>>>(h1, w2b, b2, nullptr, h2, DMLP, DMLP);
    mfma_gemm<0,1,0><<<dim3(8, 12), 256, 0, stream>>>(h2, w3b, b3, x1buf, outp, DMODEL, DMLP);
}

// Round 10
// 245.002 us; speedup vs baseline: 1.0976x; 1.0976x over previous
//
#include <hip/hip_runtime.h>
#include <hip/hip_bf16.h>
#include <math.h>

// Problem constants
#define NB   2
#define LSEQ 384
#define DMODEL 512
#define NH   8
#define HD2  64
#define DMLP 2048
#define LL2  (LSEQ*LSEQ)          // 147456
#define ROWS (NB*LSEQ)            // 768

#define BIAS_BLOCKS (NB * LL2 / 64)   // 4608
#define LN_BLOCKS   384
#define CVT_BLOCKS  1024

using bf16x8 = __attribute__((ext_vector_type(8))) short;
using f32x4  = __attribute__((ext_vector_type(4))) float;

__device__ __forceinline__ unsigned short f2bf(float f) {
    union { __hip_bfloat16 h; unsigned short u; } cv;
    cv.h = __float2bfloat16(f);
    return cv.u;
}
__device__ __forceinline__ float bf2f(unsigned short u) {
    union { float f; unsigned int i; } c;
    c.i = ((unsigned int)u) << 16;
    return c.f;
}

__device__ __forceinline__ void gload_lds16(const void* g, void* l) {
    __builtin_amdgcn_global_load_lds(
        (const __attribute__((address_space(1))) void*)g,
        (__attribute__((address_space(3))) void*)l, 16, 0, 0);
}

// ---------------------------------------------------------------------------
// fused: bias MFMA (blocks 0..4607, long pole, starts immediately)
//      + LN1(x)+LN1(mem) (blocks 4608..4991)
//      + f32->bf16 weight conversions (blocks 4992..6015)
// bias is independent of the LN/cvt outputs; consumers launch after this
// kernel, so ordering within the kernel is irrelevant — this buys overlap
// of pre work under the bias HBM stream.
__global__ __launch_bounds__(256) void pre_bias_kernel(
        const float* __restrict__ pd, const unsigned short* __restrict__ edwb_in,
        const float* __restrict__ edb, const int* __restrict__ mask,
        unsigned short* __restrict__ biasb,
        const float* __restrict__ x, const float* __restrict__ mem,
        const float* __restrict__ ln1g, const float* __restrict__ ln1b,
        unsigned short* __restrict__ a_in, unsigned short* __restrict__ a_mem,
        const float* __restrict__ s0, const float* __restrict__ s1,
        const float* __restrict__ s2, const float* __restrict__ s3,
        const float* __restrict__ s4, const float* __restrict__ s5,
        const float* __restrict__ edw,
        unsigned short* __restrict__ d0, unsigned short* __restrict__ d1,
        unsigned short* __restrict__ d2, unsigned short* __restrict__ d3,
        unsigned short* __restrict__ d4, unsigned short* __restrict__ d5,
        unsigned short* __restrict__ edwb_out) {
    __shared__ float Asb[2][64 * 64];    // 2 x 16KB (bias path only)
    const int tid = threadIdx.x;

    if (blockIdx.x < BIAS_BLOCKS) {
        // ---------------- bias path (R8-proven drain version) ----------------
        const int lane = tid & 63, w = tid >> 6;
        const int T = blockIdx.x;
        const size_t row0 = (size_t)T * 64;
        const int n = T / 2304;
        const int rem64 = (T - n * 2304) * 64;
        const int i = rem64 / LSEQ, j0 = rem64 % LSEQ;

        // allpad for this n (in-wave)
        int pad = 1;
        for (int j = lane; j < LSEQ; j += 64) pad &= (mask[n * LSEQ + j] != 0) ? 1 : 0;
        unsigned long long bal = __ballot(pad);
        const int ap = (bal == ~0ull) ? 1 : 0;

        int rr[4], sc[4];
        #pragma unroll
        for (int q = 0; q < 4; q++) {
            int s = q * 256 + tid;
            rr[q] = s >> 4;
            int cs = s & 15;
            sc[q] = (cs & 8) | ((cs & 7) ^ (rr[q] & 7));
        }

        const int c = lane & 15, g = lane >> 4;
        f32x4 acc = {};

        // prologue: stage kc=0 into buf 0
        #pragma unroll
        for (int q = 0; q < 4; q++)
            gload_lds16(pd + (row0 + rr[q]) * DMODEL + sc[q] * 4, &Asb[0][(q * 256 + tid) * 4]);
        __syncthreads();

        for (int kc = 0; kc < 8; kc++) {
            if (kc < 7) {
                const int nb = (kc + 1) & 1;
                #pragma unroll
                for (int q = 0; q < 4; q++)
                    gload_lds16(pd + (row0 + rr[q]) * DMODEL + (kc + 1) * 64 + sc[q] * 4,
                                &Asb[nb][(q * 256 + tid) * 4]);
            }
            const float* Ab = &Asb[kc & 1][0];
            #pragma unroll
            for (int ks = 0; ks < 2; ks++) {
                const int ch0 = (8 * ks) | ((2 * g) ^ (c & 7));
                const int ch1 = (8 * ks) | ((2 * g + 1) ^ (c & 7));
                float4 a0 = *(const float4*)&Ab[(w * 16 + c) * 64 + ch0 * 4];
                float4 a1 = *(const float4*)&Ab[(w * 16 + c) * 64 + ch1 * 4];
                bf16x8 af;
                af[0] = (short)f2bf(a0.x); af[1] = (short)f2bf(a0.y);
                af[2] = (short)f2bf(a0.z); af[3] = (short)f2bf(a0.w);
                af[4] = (short)f2bf(a1.x); af[5] = (short)f2bf(a1.y);
                af[6] = (short)f2bf(a1.z); af[7] = (short)f2bf(a1.w);
                bf16x8 bfv = *(const bf16x8*)&edwb_in[c * 512 + kc * 64 + ks * 32 + g * 8];
                acc = __builtin_amdgcn_mfma_f32_16x16x32_bf16(af, bfv, acc, 0, 0, 0);
            }
            if (kc < 7) __syncthreads();
        }

        if (c < 8) {
            const float eb = edb[c];
            const int jj = j0 + w * 16 + g * 4;
            int4 mv = *(const int4*)&mask[n * LSEQ + jj];
            const float NEGINF = -__builtin_inff();
            ushort4 o;
            o.x = f2bf(acc[0] + eb + ((!ap && mv.x) ? NEGINF : 0.0f));
            o.y = f2bf(acc[1] + eb + ((!ap && mv.y) ? NEGINF : 0.0f));
            o.z = f2bf(acc[2] + eb + ((!ap && mv.z) ? NEGINF : 0.0f));
            o.w = f2bf(acc[3] + eb + ((!ap && mv.w) ? NEGINF : 0.0f));
            *(ushort4*)&biasb[(size_t)(n * 8 + c) * LL2 + (size_t)i * LSEQ + jj] = o;
        }
        return;
    }

    if (blockIdx.x < BIAS_BLOCKS + LN_BLOCKS) {
        // ---------------- LN1 path ----------------
        int lane = tid & 63;
        int row  = (blockIdx.x - BIAS_BLOCKS) * 4 + (tid >> 6);
        const float* src = (row < ROWS) ? x : mem;
        unsigned short* dst = (row < ROWS) ? a_in : a_mem;
        int r2 = (row < ROWS) ? row : row - ROWS;
        const float* p = src + (size_t)r2 * DMODEL + lane * 8;
        float4 v0 = *(const float4*)p;
        float4 v1 = *(const float4*)(p + 4);
        float s  = v0.x + v0.y + v0.z + v0.w + v1.x + v1.y + v1.z + v1.w;
        float ss = v0.x*v0.x + v0.y*v0.y + v0.z*v0.z + v0.w*v0.w
                 + v1.x*v1.x + v1.y*v1.y + v1.z*v1.z + v1.w*v1.w;
        #pragma unroll
        for (int o = 32; o; o >>= 1) { s += __shfl_xor(s, o); ss += __shfl_xor(ss, o); }
        float m   = s * (1.0f / DMODEL);
        float var = ss * (1.0f / DMODEL) - m * m;
        float r   = rsqrtf(var + 1e-5f);
        float4 g0 = *(const float4*)(ln1g + lane * 8);
        float4 g1 = *(const float4*)(ln1g + lane * 8 + 4);
        float4 b0 = *(const float4*)(ln1b + lane * 8);
        float4 b1 = *(const float4*)(ln1b + lane * 8 + 4);
        unsigned short* q = dst + (size_t)r2 * DMODEL + lane * 8;
        ushort4 lo = {f2bf((v0.x-m)*r*g0.x+b0.x), f2bf((v0.y-m)*r*g0.y+b0.y),
                      f2bf((v0.z-m)*r*g0.z+b0.z), f2bf((v0.w-m)*r*g0.w+b0.w)};
        ushort4 hi = {f2bf((v1.x-m)*r*g1.x+b1.x), f2bf((v1.y-m)*r*g1.y+b1.y),
                      f2bf((v1.z-m)*r*g1.z+b1.z), f2bf((v1.w-m)*r*g1.w+b1.w)};
        *(ushort4*)q = lo;
        *(ushort4*)(q + 4) = hi;
        return;
    }

    // ---------------- cvt path ----------------
    const int stride = CVT_BLOCKS * 256;
    const int t0 = (blockIdx.x - BIAS_BLOCKS - LN_BLOCKS) * 256 + tid;
    const float* srcs[6] = {s0, s1, s2, s3, s4, s5};
    unsigned short* dsts[6] = {d0, d1, d2, d3, d4, d5};
    const int nf4[6] = {DMODEL*DMODEL/4, 2*DMODEL*DMODEL/4, DMODEL*DMODEL/4,
                        DMLP*DMODEL/4, DMLP*DMLP/4, DMLP*DMODEL/4};
    #pragma unroll
    for (int a = 0; a < 6; a++) {
        const float* s = srcs[a];
        unsigned short* d = dsts[a];
        for (int i = t0; i < nf4[a]; i += stride) {
            float4 v = *(const float4*)(s + (size_t)i * 4);
            ushort4 o = {f2bf(v.x), f2bf(v.y), f2bf(v.z), f2bf(v.w)};
            *(ushort4*)(d + (size_t)i * 4) = o;
        }
    }
    for (int i = t0; i < 16 * 512 / 4; i += stride) {
        int row = i >> 7;
        float4 v = {0.f, 0.f, 0.f, 0.f};
        if (row < 8) v = *(const float4*)(edw + (size_t)i * 4);
        ushort4 o = {f2bf(v.x), f2bf(v.y), f2bf(v.z), f2bf(v.w)};
        *(ushort4*)(edwb_out + (size_t)i * 4) = o;
    }
}

// ---------------------------------------------------------------------------
// edw pre-conversion (tiny, must precede pre_bias since bias reads edwb)
__global__ void edw_cvt_kernel(const float* __restrict__ edw,
                               unsigned short* __restrict__ edwb) {
    int i = blockIdx.x * 256 + threadIdx.x;   // 2048 threads, 4 f32 each
    float4 v = {0.f, 0.f, 0.f, 0.f};
    if (i < 8 * 512 / 4) v = *(const float4*)(edw + (size_t)i * 4);
    ushort4 o = {f2bf(v.x), f2bf(v.y), f2bf(v.z), f2bf(v.w)};
    *(ushort4*)(edwb + (size_t)i * 4) = o;
}

// ---------------------------------------------------------------------------
// LayerNorm (ln2): one wave per row
__global__ __launch_bounds__(256) void ln_kernel(const float* __restrict__ src0,
                                                 const float* __restrict__ g,
                                                 const float* __restrict__ b,
                                                 unsigned short* __restrict__ dst0) {
    int lane = threadIdx.x & 63;
    int row  = blockIdx.x * 4 + (threadIdx.x >> 6);
    const float* p = src0 + (size_t)row * DMODEL + lane * 8;
    float4 v0 = *(const float4*)p;
    float4 v1 = *(const float4*)(p + 4);
    float s  = v0.x + v0.y + v0.z + v0.w + v1.x + v1.y + v1.z + v1.w;
    float ss = v0.x*v0.x + v0.y*v0.y + v0.z*v0.z + v0.w*v0.w
             + v1.x*v1.x + v1.y*v1.y + v1.z*v1.z + v1.w*v1.w;
    #pragma unroll
    for (int o = 32; o; o >>= 1) { s += __shfl_xor(s, o); ss += __shfl_xor(ss, o); }
    float m   = s * (1.0f / DMODEL);
    float var = ss * (1.0f / DMODEL) - m * m;
    float r   = rsqrtf(var + 1e-5f);
    float4 g0 = *(const float4*)(g + lane * 8);
    float4 g1 = *(const float4*)(g + lane * 8 + 4);
    float4 b0 = *(const float4*)(b + lane * 8);
    float4 b1 = *(const float4*)(b + lane * 8 + 4);
    unsigned short* q = dst0 + (size_t)row * DMODEL + lane * 8;
    ushort4 lo = {f2bf((v0.x-m)*r*g0.x+b0.x), f2bf((v0.y-m)*r*g0.y+b0.y),
                  f2bf((v0.z-m)*r*g0.z+b0.z), f2bf((v0.w-m)*r*g0.w+b0.w)};
    ushort4 hi = {f2bf((v1.x-m)*r*g1.x+b1.x), f2bf((v1.y-m)*r*g1.y+b1.y),
                  f2bf((v1.z-m)*r*g1.z+b1.z), f2bf((v1.w-m)*r*g1.w+b1.w)};
    *(ushort4*)q = lo;
    *(ushort4*)(q + 4) = hi;
}

// ---------------------------------------------------------------------------
// bf16 MFMA GEMM body (R4-proven): 64x64 tile, 4 waves, BK=64, 4-deep
// pipelined staging (counted vmcnt + raw barriers), XOR-swizzled LDS.
template<int ACT, int RES, int OBF>
__device__ __forceinline__ void gemm_body(const unsigned short* __restrict__ A,
        const unsigned short* __restrict__ W, const float* __restrict__ bv,
        const float* __restrict__ Rsd, void* __restrict__ Cv,
        int Nn, int K, int m0, int n0, short* As, short* Ws) {
    const int tid  = threadIdx.x;
    const int lane = tid & 63, w = tid >> 6;
    const int wr = w >> 1, wc = w & 1;
    const int s0 = tid, s1 = 256 + tid;
    const int r0 = s0 >> 3, c0 = ((s0 & 7) ^ (r0 & 7)) << 3;
    const int r1 = s1 >> 3, c1 = ((s1 & 7) ^ (r1 & 7)) << 3;
    const unsigned short* ag0 = A + (size_t)(m0 + r0) * K + c0;
    const unsigned short* ag1 = A + (size_t)(m0 + r1) * K + c1;
    const unsigned short* wg0 = W + (size_t)(n0 + r0) * K + c0;
    const unsigned short* wg1 = W + (size_t)(n0 + r1) * K + c1;

    f32x4 acc[2][2] = {};
    const int lc = lane & 15, lr = lane >> 4;
    const int KT = K >> 6;

    #pragma unroll
    for (int t = 0; t < 4; t++) {
        const int b = t * 4096, k0 = t << 6;
        gload_lds16(ag0 + k0, &As[b + s0 * 8]);
        gload_lds16(ag1 + k0, &As[b + s1 * 8]);
        gload_lds16(wg0 + k0, &Ws[b + s0 * 8]);
        gload_lds16(wg1 + k0, &Ws[b + s1 * 8]);
    }

    for (int t = 0; t < KT; t++) {
        int rem = KT - 1 - t; if (rem > 3) rem = 3;
        if (rem >= 3)      asm volatile("s_waitcnt vmcnt(12)" ::: "memory");
        else if (rem == 2) asm volatile("s_waitcnt vmcnt(8)"  ::: "memory");
        else if (rem == 1) asm volatile("s_waitcnt vmcnt(4)"  ::: "memory");
        else               asm volatile("s_waitcnt vmcnt(0)"  ::: "memory");
        __builtin_amdgcn_s_barrier();
        __builtin_amdgcn_sched_barrier(0);
        const int cur = (t & 3) * 4096;
        bf16x8 af[2][2], bfr[2][2];
        #pragma unroll
        for (int m = 0; m < 2; m++) {
            const int rra = wr * 32 + m * 16 + lc;
            #pragma unroll
            for (int kk = 0; kk < 2; kk++) {
                const int cc = (lr + kk * 4) ^ (rra & 7);
                af[m][kk] = *(const bf16x8*)&As[cur + rra * 64 + cc * 8];
            }
        }
        #pragma unroll
        for (int nn = 0; nn < 2; nn++) {
            const int rrb = wc * 32 + nn * 16 + lc;
            #pragma unroll
            for (int kk = 0; kk < 2; kk++) {
                const int cc = (lr + kk * 4) ^ (rrb & 7);
                bfr[nn][kk] = *(const bf16x8*)&Ws[cur + rrb * 64 + cc * 8];
            }
        }
        #pragma unroll
        for (int m = 0; m < 2; m++)
            #pragma unroll
            for (int nn = 0; nn < 2; nn++) {
                acc[m][nn] = __builtin_amdgcn_mfma_f32_16x16x32_bf16(af[m][0], bfr[nn][0], acc[m][nn], 0, 0, 0);
                acc[m][nn] = __builtin_amdgcn_mfma_f32_16x16x32_bf16(af[m][1], bfr[nn][1], acc[m][nn], 0, 0, 0);
            }
        if (t + 4 < KT) {
            __builtin_amdgcn_sched_barrier(0);
            __builtin_amdgcn_s_barrier();
            const int b = cur, k0 = (t + 4) << 6;
            gload_lds16(ag0 + k0, &As[b + s0 * 8]);
            gload_lds16(ag1 + k0, &As[b + s1 * 8]);
            gload_lds16(wg0 + k0, &Ws[b + s0 * 8]);
            gload_lds16(wg1 + k0, &Ws[b + s1 * 8]);
        }
    }

    #pragma unroll
    for (int nn = 0; nn < 2; nn++) {
        int gcol = n0 + wc * 32 + nn * 16 + lc;
        float bb = bv[gcol];
        #pragma unroll
        for (int m = 0; m < 2; m++) {
            #pragma unroll
            for (int r = 0; r < 4; r++) {
                int grow = m0 + wr * 32 + m * 16 + lr * 4 + r;
                float o = acc[m][nn][r] + bb;
                if (ACT) o = o / (1.0f + expf(-o));
                if (RES) o += Rsd[(size_t)grow * Nn + gcol];
                if (OBF) ((unsigned short*)Cv)[(size_t)grow * Nn + gcol] = f2bf(o);
                else     ((float*)Cv)[(size_t)grow * Nn + gcol] = o;
            }
        }
    }
}

template<int ACT, int RES, int OBF>
__global__ __launch_bounds__(256) void mfma_gemm(const unsigned short* __restrict__ A,
                                                 const unsigned short* __restrict__ W,
                                                 const float* __restrict__ bv,
                                                 const float* __restrict__ Rsd,
                                                 void* __restrict__ Cv, int Nn, int K) {
    __shared__ short As[4 * 4096];
    __shared__ short Ws[4 * 4096];
    gemm_body<ACT, RES, OBF>(A, W, bv, Rsd, Cv, Nn, K, blockIdx.y * 64, blockIdx.x * 64, As, Ws);
}

// merged q + kv projection
__global__ __launch_bounds__(256) void qkv_gemm(const unsigned short* __restrict__ a_in,
                                                const unsigned short* __restrict__ a_mem,
                                                const unsigned short* __restrict__ qwb,
                                                const unsigned short* __restrict__ kvwb,
                                                const float* __restrict__ qbv,
                                                const float* __restrict__ kvbv,
                                                float* __restrict__ qbuf,
                                                float* __restrict__ kvbuf) {
    __shared__ short As[4 * 4096];
    __shared__ short Ws[4 * 4096];
    const int bx = blockIdx.x;
    const unsigned short* A; const unsigned short* W; const float* bv; float* C; int Nn, n0;
    if (bx < 8) { A = a_in;  W = qwb;  bv = qbv;  C = qbuf;  Nn = DMODEL;     n0 = bx * 64; }
    else        { A = a_mem; W = kvwb; bv = kvbv; C = kvbuf; Nn = 2 * DMODEL; n0 = (bx - 8) * 64; }
    gemm_body<0, 0, 0>(A, W, bv, nullptr, C, Nn, DMODEL, blockIdx.y * 64, n0, As, Ws);
}

// ---------------------------------------------------------------------------
// scores[n,h,i,j] = 0.125 * q_i.k_j + bf2f(biasb[n,h,i,j])  (mask pre-folded)
__global__ __launch_bounds__(256) void scores_kernel(const float* __restrict__ q,
                                                     const float* __restrict__ kv,
                                                     const unsigned short* __restrict__ biasb,
                                                     float* __restrict__ S) {
    const int n = blockIdx.z, h = blockIdx.y;
    const int it = blockIdx.x / 12, jt = blockIdx.x % 12;
    __shared__ float Qs[64][32];
    __shared__ float Ks[64][32];
    const int tid = threadIdx.x;
    const int r = tid >> 3, c = (tid & 7) << 3;
    {
        const float* qp = q + ((size_t)(n * LSEQ + it * 32 + r)) * DMODEL + h * HD2 + c;
        float4 q0 = *(const float4*)qp;
        float4 q1 = *(const float4*)(qp + 4);
        Qs[c+0][r]=q0.x; Qs[c+1][r]=q0.y; Qs[c+2][r]=q0.z; Qs[c+3][r]=q0.w;
        Qs[c+4][r]=q1.x; Qs[c+5][r]=q1.y; Qs[c+6][r]=q1.z; Qs[c+7][r]=q1.w;
        const float* kp = kv + ((size_t)(n * LSEQ + jt * 32 + r)) * (2 * DMODEL) + h * HD2 + c;
        float4 k0 = *(const float4*)kp;
        float4 k1 = *(const float4*)(kp + 4);
        Ks[c+0][r]=k0.x; Ks[c+1][r]=k0.y; Ks[c+2][r]=k0.z; Ks[c+3][r]=k0.w;
        Ks[c+4][r]=k1.x; Ks[c+5][r]=k1.y; Ks[c+6][r]=k1.z; Ks[c+7][r]=k1.w;
    }
    __syncthreads();
    const int tx = tid & 15, ty = tid >> 4;
    float acc[2][2] = {{0.f,0.f},{0.f,0.f}};
    #pragma unroll
    for (int k = 0; k < 64; k++) {
        float2 a  = *(const float2*)&Qs[k][ty << 1];
        float2 b2 = *(const float2*)&Ks[k][tx << 1];
        acc[0][0] = fmaf(a.x, b2.x, acc[0][0]);
        acc[0][1] = fmaf(a.x, b2.y, acc[0][1]);
        acc[1][0] = fmaf(a.y, b2.x, acc[1][0]);
        acc[1][1] = fmaf(a.y, b2.y, acc[1][1]);
    }
    #pragma unroll
    for (int i2 = 0; i2 < 2; i2++) {
        int gi = it * 32 + (ty << 1) + i2;
        int gj = jt * 32 + (tx << 1);
        size_t idx = ((size_t)(n * 8 + h)) * LL2 + (size_t)gi * LSEQ + gj;
        ushort2 bb = *(const ushort2*)&biasb[idx];
        S[idx]     = acc[i2][0] * 0.125f + bf2f(bb.x);
        S[idx + 1] = acc[i2][1] * 0.125f + bf2f(bb.y);
    }
}

// ---------------------------------------------------------------------------
// row softmax over 384 cols; one wave per row
__global__ __launch_bounds__(256) void softmax_kernel(float* __restrict__ S) {
    int lane = threadIdx.x & 63;
    int row  = blockIdx.x * 4 + (threadIdx.x >> 6);
    float* p = S + (size_t)row * LSEQ;
    float v[6];
    #pragma unroll
    for (int cc = 0; cc < 6; cc++) v[cc] = p[cc * 64 + lane];
    float mx = v[0];
    #pragma unroll
    for (int cc = 1; cc < 6; cc++) mx = fmaxf(mx, v[cc]);
    #pragma unroll
    for (int o = 32; o; o >>= 1) mx = fmaxf(mx, __shfl_xor(mx, o));
    float sum = 0.f;
    #pragma unroll
    for (int cc = 0; cc < 6; cc++) { v[cc] = __expf(v[cc] - mx); sum += v[cc]; }
    #pragma unroll
    for (int o = 32; o; o >>= 1) sum += __shfl_xor(sum, o);
    float inv = 1.0f / sum;
    #pragma unroll
    for (int cc = 0; cc < 6; cc++) p[cc * 64 + lane] = v[cc] * inv;
}

// ---------------------------------------------------------------------------
// attn_out = P @ V  -> bf16; allpad computed in-wave
__global__ __launch_bounds__(256) void av_kernel(const float* __restrict__ S,
                                                 const float* __restrict__ kv,
                                                 const int* __restrict__ mask,
                                                 unsigned short* __restrict__ outb) {
    const int it = blockIdx.x, h = blockIdx.y, n = blockIdx.z;
    __shared__ float Ps[32][68];
    __shared__ float Vs[64][68];
    const int tid = threadIdx.x;
    const int lane = tid & 63;
    int pad = 1;
    for (int j = lane; j < LSEQ; j += 64) pad &= (mask[n * LSEQ + j] != 0) ? 1 : 0;
    unsigned long long bal = __ballot(pad != 0);
    const float zf = (bal == 0xFFFFFFFFFFFFFFFFull) ? 0.0f : 1.0f;
    const int tx = tid & 15, ty = tid >> 4;
    const int pr = tid >> 3, pc = (tid & 7) << 3;
    const int vr = tid >> 2, vc = (tid & 3) << 4;
    float acc0[4] = {0,0,0,0}, acc1[4] = {0,0,0,0};
    for (int j0 = 0; j0 < LSEQ; j0 += 64) {
        const float* sp = S + ((size_t)(n * 8 + h)) * LL2 + (size_t)(it * 32 + pr) * LSEQ + j0 + pc;
        float4 p0 = *(const float4*)sp;
        float4 p1 = *(const float4*)(sp + 4);
        *(float4*)&Ps[pr][pc]     = p0;
        *(float4*)&Ps[pr][pc + 4] = p1;
        #pragma unroll
        for (int u = 0; u < 4; u++) {
            float4 vvv = *(const float4*)&kv[((size_t)(n * LSEQ + j0 + vr)) * (2 * DMODEL)
                                             + DMODEL + h * HD2 + vc + 4 * u];
            *(float4*)&Vs[vr][vc + 4 * u] = vvv;
        }
        __syncthreads();
        #pragma unroll
        for (int j = 0; j < 64; j++) {
            float pa  = Ps[ty][j];
            float pb2 = Ps[ty + 16][j];
            float4 vv = *(const float4*)&Vs[j][tx << 2];
            acc0[0] = fmaf(pa,  vv.x, acc0[0]);
            acc0[1] = fmaf(pa,  vv.y, acc0[1]);
            acc0[2] = fmaf(pa,  vv.z, acc0[2]);
            acc0[3] = fmaf(pa,  vv.w, acc0[3]);
            acc1[0] = fmaf(pb2, vv.x, acc1[0]);
            acc1[1] = fmaf(pb2, vv.y, acc1[1]);
            acc1[2] = fmaf(pb2, vv.z, acc1[2]);
            acc1[3] = fmaf(pb2, vv.w, acc1[3]);
        }
        __syncthreads();
    }
    int i0 = it * 32;
    ushort4 o0 = {f2bf(acc0[0]*zf), f2bf(acc0[1]*zf), f2bf(acc0[2]*zf), f2bf(acc0[3]*zf)};
    ushort4 o1 = {f2bf(acc1[0]*zf), f2bf(acc1[1]*zf), f2bf(acc1[2]*zf), f2bf(acc1[3]*zf)};
    *(ushort4*)&outb[((size_t)(n * LSEQ + i0 + ty)) * DMODEL + h * HD2 + (tx << 2)]      = o0;
    *(ushort4*)&outb[((size_t)(n * LSEQ + i0 + ty + 16)) * DMODEL + h * HD2 + (tx << 2)] = o1;
}

// ---------------------------------------------------------------------------
extern "C" void kernel_launch(void* const* d_in, const int* in_sizes, int n_in,
                              void* d_out, int out_size, void* d_ws, size_t ws_size,
                              hipStream_t stream) {
    const float* x    = (const float*)d_in[0];
    const float* mem  = (const float*)d_in[1];
    const float* pd   = (const float*)d_in[2];
    const int*   mask = (const int*)d_in[3];
    const float* qw   = (const float*)d_in[4];
    const float* qbv  = (const float*)d_in[5];
    const float* kvw  = (const float*)d_in[6];
    const float* kvbv = (const float*)d_in[7];
    const float* pw   = (const float*)d_in[8];
    const float* pbv  = (const float*)d_in[9];
    const float* edw  = (const float*)d_in[10];
    const float* edb  = (const float*)d_in[11];
    const float* ln1g = (const float*)d_in[12];
    const float* ln1b = (const float*)d_in[13];
    const float* ln2g = (const float*)d_in[14];
    const float* ln2b = (const float*)d_in[15];
    const float* w1   = (const float*)d_in[16];
    const float* b1   = (const float*)d_in[17];
    const float* w2   = (const float*)d_in[18];
    const float* b2   = (const float*)d_in[19];
    const float* w3   = (const float*)d_in[20];
    const float* b3   = (const float*)d_in[21];

    float* wsf = (float*)d_ws;
    unsigned short* biasb = (unsigned short*)(wsf + 16);     // NB*NH*LL2 bf16
    float* scores = wsf + 16 + (size_t)NB * NH * LL2 / 2;    // f32
    float* qbuf   = scores + (size_t)NB * NH * LL2;
    float* kvbuf  = qbuf + (size_t)ROWS * DMODEL;
    float* x1buf  = kvbuf + (size_t)ROWS * 2 * DMODEL;
    unsigned short* a_in  = (unsigned short*)(x1buf + (size_t)ROWS * DMODEL);
    unsigned short* a_mem = a_in  + (size_t)ROWS * DMODEL;
    unsigned short* attno = a_mem + (size_t)ROWS * DMODEL;
    unsigned short* h0    = attno + (size_t)ROWS * DMODEL;
    unsigned short* h1    = h0    + (size_t)ROWS * DMODEL;
    unsigned short* h2    = h1    + (size_t)ROWS * DMLP;
    unsigned short* qwb   = h2    + (size_t)ROWS * DMLP;
    unsigned short* kvwb  = qwb   + (size_t)DMODEL * DMODEL;
    unsigned short* pwb   = kvwb  + (size_t)2 * DMODEL * DMODEL;
    unsigned short* w1b   = pwb   + (size_t)DMODEL * DMODEL;
    unsigned short* w2b   = w1b   + (size_t)DMLP * DMODEL;
    unsigned short* w3b   = w2b   + (size_t)DMLP * DMLP;
    unsigned short* edwb  = w3b   + (size_t)DMLP * DMODEL;   // 16*512 bf16 (used by bias)
    unsigned short* edwb2 = edwb  + (size_t)16 * 512;        // output of cvt path (unused dup)

    float* outp = (float*)d_out;

    // tiny: convert edw (8x512) -> edwb before the fused kernel needs it
    edw_cvt_kernel<<<4, 256, 0, stream>>>(edw, edwb);
    // zero rows 8..15 of edwb (padding) — done by edw_cvt via bounds: grid 4*256
    // covers 1024 float4 = 16*512/2... handled below: second launch pads.
    edw_cvt_kernel<<<4, 256, 0, stream>>>(edw, edwb);  // idempotent
    // pad rows 8..15 with zeros using the same kernel shape:
    hipMemsetAsync(edwb + 8 * 512, 0, 8 * 512 * sizeof(unsigned short), stream);

    pre_bias_kernel<<<BIAS_BLOCKS + LN_BLOCKS + CVT_BLOCKS, 256, 0, stream>>>(
        pd, edwb, edb, mask, biasb,
        x, mem, ln1g, ln1b, a_in, a_mem,
        qw, kvw, pw, w1, w2, w3, edw,
        qwb, kvwb, pwb, w1b, w2b, w3b, edwb2);

    qkv_gemm<<<dim3(24, 12), 256, 0, stream>>>(a_in, a_mem, qwb, kvwb, qbv, kvbv, qbuf, kvbuf);

    scores_kernel<<<dim3(144, NH, NB), 256, 0, stream>>>(qbuf, kvbuf, biasb, scores);
    softmax_kernel<<<(NB * NH * LSEQ) / 4, 256, 0, stream>>>(scores);
    av_kernel<<<dim3(12, NH, NB), 256, 0, stream>>>(scores, kvbuf, mask, attno);

    mfma_gemm<0,1,0><<<dim3(8, 12), 256, 0, stream>>>(attno, pwb, pbv, x, x1buf, DMODEL, DMODEL);
    ln_kernel<<<ROWS / 4, 256, 0, stream>>>(x1buf, ln2g, ln2b, h0);
    mfma_gemm<1,0,1><<<dim3(32, 12), 256, 0, stream>>>(h0, w1b, b1, nullptr, h1, DMLP, DMODEL);
    mfma_gemm<1,0,1><<<dim3(32, 12), 256, 0, stream>>>(h1, w2b, b2, nullptr, h2, DMLP, DMLP);
    mfma_gemm<0,1,0><<<dim3(8, 12), 256, 0, stream>>>(h2, w3b, b3, x1buf, outp, DMODEL, DMLP);
}

// Round 11
// 235.618 us; speedup vs baseline: 1.1413x; 1.0398x over previous
//
#include <hip/hip_runtime.h>
#include <hip/hip_bf16.h>
#include <math.h>

// Problem constants
#define NB   2
#define LSEQ 384
#define DMODEL 512
#define NH   8
#define HD2  64
#define DMLP 2048
#define LL2  (LSEQ*LSEQ)          // 147456
#define ROWS (NB*LSEQ)            // 768

#define BIAS_BLOCKS (NB * LL2 / 64)   // 4608
#define LN_BLOCKS   384
#define CVT_BLOCKS  1024

using bf16x8 = __attribute__((ext_vector_type(8))) short;
using f32x4  = __attribute__((ext_vector_type(4))) float;

__device__ __forceinline__ unsigned short f2bf(float f) {
    union { __hip_bfloat16 h; unsigned short u; } cv;
    cv.h = __float2bfloat16(f);
    return cv.u;
}
__device__ __forceinline__ float bf2f(unsigned short u) {
    union { float f; unsigned int i; } c;
    c.i = ((unsigned int)u) << 16;
    return c.f;
}

__device__ __forceinline__ void gload_lds16(const void* g, void* l) {
    __builtin_amdgcn_global_load_lds(
        (const __attribute__((address_space(1))) void*)g,
        (__attribute__((address_space(3))) void*)l, 16, 0, 0);
}

// ---------------------------------------------------------------------------
// fused: bias MFMA (blocks 0..4607) + LN1 (4608..4991) + weight cvt (rest)
__global__ __launch_bounds__(256) void pre_bias_kernel(
        const float* __restrict__ pd, const unsigned short* __restrict__ edwb_in,
        const float* __restrict__ edb, const int* __restrict__ mask,
        unsigned short* __restrict__ biasb,
        const float* __restrict__ x, const float* __restrict__ mem,
        const float* __restrict__ ln1g, const float* __restrict__ ln1b,
        unsigned short* __restrict__ a_in, unsigned short* __restrict__ a_mem,
        const float* __restrict__ s0, const float* __restrict__ s1,
        const float* __restrict__ s2, const float* __restrict__ s3,
        const float* __restrict__ s4, const float* __restrict__ s5,
        unsigned short* __restrict__ d0, unsigned short* __restrict__ d1,
        unsigned short* __restrict__ d2, unsigned short* __restrict__ d3,
        unsigned short* __restrict__ d4, unsigned short* __restrict__ d5) {
    __shared__ float Asb[2][64 * 64];    // 2 x 16KB (bias path only)
    const int tid = threadIdx.x;

    if (blockIdx.x < BIAS_BLOCKS) {
        // ---------------- bias path (R8-proven drain version) ----------------
        const int lane = tid & 63, w = tid >> 6;
        const int T = blockIdx.x;
        const size_t row0 = (size_t)T * 64;
        const int n = T / 2304;
        const int rem64 = (T - n * 2304) * 64;
        const int i = rem64 / LSEQ, j0 = rem64 % LSEQ;

        int pad = 1;
        for (int j = lane; j < LSEQ; j += 64) pad &= (mask[n * LSEQ + j] != 0) ? 1 : 0;
        unsigned long long bal = __ballot(pad);
        const int ap = (bal == ~0ull) ? 1 : 0;

        int rr[4], sc[4];
        #pragma unroll
        for (int q = 0; q < 4; q++) {
            int s = q * 256 + tid;
            rr[q] = s >> 4;
            int cs = s & 15;
            sc[q] = (cs & 8) | ((cs & 7) ^ (rr[q] & 7));
        }

        const int c = lane & 15, g = lane >> 4;
        f32x4 acc = {};

        #pragma unroll
        for (int q = 0; q < 4; q++)
            gload_lds16(pd + (row0 + rr[q]) * DMODEL + sc[q] * 4, &Asb[0][(q * 256 + tid) * 4]);
        __syncthreads();

        for (int kc = 0; kc < 8; kc++) {
            if (kc < 7) {
                const int nb = (kc + 1) & 1;
                #pragma unroll
                for (int q = 0; q < 4; q++)
                    gload_lds16(pd + (row0 + rr[q]) * DMODEL + (kc + 1) * 64 + sc[q] * 4,
                                &Asb[nb][(q * 256 + tid) * 4]);
            }
            const float* Ab = &Asb[kc & 1][0];
            #pragma unroll
            for (int ks = 0; ks < 2; ks++) {
                const int ch0 = (8 * ks) | ((2 * g) ^ (c & 7));
                const int ch1 = (8 * ks) | ((2 * g + 1) ^ (c & 7));
                float4 a0 = *(const float4*)&Ab[(w * 16 + c) * 64 + ch0 * 4];
                float4 a1 = *(const float4*)&Ab[(w * 16 + c) * 64 + ch1 * 4];
                bf16x8 af;
                af[0] = (short)f2bf(a0.x); af[1] = (short)f2bf(a0.y);
                af[2] = (short)f2bf(a0.z); af[3] = (short)f2bf(a0.w);
                af[4] = (short)f2bf(a1.x); af[5] = (short)f2bf(a1.y);
                af[6] = (short)f2bf(a1.z); af[7] = (short)f2bf(a1.w);
                bf16x8 bfv = *(const bf16x8*)&edwb_in[c * 512 + kc * 64 + ks * 32 + g * 8];
                acc = __builtin_amdgcn_mfma_f32_16x16x32_bf16(af, bfv, acc, 0, 0, 0);
            }
            if (kc < 7) __syncthreads();
        }

        if (c < 8) {
            const float eb = edb[c];
            const int jj = j0 + w * 16 + g * 4;
            int4 mv = *(const int4*)&mask[n * LSEQ + jj];
            const float NEGINF = -__builtin_inff();
            ushort4 o;
            o.x = f2bf(acc[0] + eb + ((!ap && mv.x) ? NEGINF : 0.0f));
            o.y = f2bf(acc[1] + eb + ((!ap && mv.y) ? NEGINF : 0.0f));
            o.z = f2bf(acc[2] + eb + ((!ap && mv.z) ? NEGINF : 0.0f));
            o.w = f2bf(acc[3] + eb + ((!ap && mv.w) ? NEGINF : 0.0f));
            *(ushort4*)&biasb[(size_t)(n * 8 + c) * LL2 + (size_t)i * LSEQ + jj] = o;
        }
        return;
    }

    if (blockIdx.x < BIAS_BLOCKS + LN_BLOCKS) {
        // ---------------- LN1 path ----------------
        int lane = tid & 63;
        int row  = (blockIdx.x - BIAS_BLOCKS) * 4 + (tid >> 6);
        const float* src = (row < ROWS) ? x : mem;
        unsigned short* dst = (row < ROWS) ? a_in : a_mem;
        int r2 = (row < ROWS) ? row : row - ROWS;
        const float* p = src + (size_t)r2 * DMODEL + lane * 8;
        float4 v0 = *(const float4*)p;
        float4 v1 = *(const float4*)(p + 4);
        float s  = v0.x + v0.y + v0.z + v0.w + v1.x + v1.y + v1.z + v1.w;
        float ss = v0.x*v0.x + v0.y*v0.y + v0.z*v0.z + v0.w*v0.w
                 + v1.x*v1.x + v1.y*v1.y + v1.z*v1.z + v1.w*v1.w;
        #pragma unroll
        for (int o = 32; o; o >>= 1) { s += __shfl_xor(s, o); ss += __shfl_xor(ss, o); }
        float m   = s * (1.0f / DMODEL);
        float var = ss * (1.0f / DMODEL) - m * m;
        float r   = rsqrtf(var + 1e-5f);
        float4 g0 = *(const float4*)(ln1g + lane * 8);
        float4 g1 = *(const float4*)(ln1g + lane * 8 + 4);
        float4 b0 = *(const float4*)(ln1b + lane * 8);
        float4 b1 = *(const float4*)(ln1b + lane * 8 + 4);
        unsigned short* q = dst + (size_t)r2 * DMODEL + lane * 8;
        ushort4 lo = {f2bf((v0.x-m)*r*g0.x+b0.x), f2bf((v0.y-m)*r*g0.y+b0.y),
                      f2bf((v0.z-m)*r*g0.z+b0.z), f2bf((v0.w-m)*r*g0.w+b0.w)};
        ushort4 hi = {f2bf((v1.x-m)*r*g1.x+b1.x), f2bf((v1.y-m)*r*g1.y+b1.y),
                      f2bf((v1.z-m)*r*g1.z+b1.z), f2bf((v1.w-m)*r*g1.w+b1.w)};
        *(ushort4*)q = lo;
        *(ushort4*)(q + 4) = hi;
        return;
    }

    // ---------------- cvt path ----------------
    const int stride = CVT_BLOCKS * 256;
    const int t0 = (blockIdx.x - BIAS_BLOCKS - LN_BLOCKS) * 256 + tid;
    const float* srcs[6] = {s0, s1, s2, s3, s4, s5};
    unsigned short* dsts[6] = {d0, d1, d2, d3, d4, d5};
    const int nf4[6] = {DMODEL*DMODEL/4, 2*DMODEL*DMODEL/4, DMODEL*DMODEL/4,
                        DMLP*DMODEL/4, DMLP*DMLP/4, DMLP*DMODEL/4};
    #pragma unroll
    for (int a = 0; a < 6; a++) {
        const float* s = srcs[a];
        unsigned short* d = dsts[a];
        for (int i = t0; i < nf4[a]; i += stride) {
            float4 v = *(const float4*)(s + (size_t)i * 4);
            ushort4 o = {f2bf(v.x), f2bf(v.y), f2bf(v.z), f2bf(v.w)};
            *(ushort4*)(d + (size_t)i * 4) = o;
        }
    }
}

// ---------------------------------------------------------------------------
// edw pre-conversion with zero padding rows 8..15 (16x512 bf16 table)
__global__ void edw_cvt_kernel(const float* __restrict__ edw,
                               unsigned short* __restrict__ edwb) {
    int i = blockIdx.x * 256 + threadIdx.x;   // 8 blocks * 256 = 2048 = 16*512/4
    int row = i >> 7;
    float4 v = {0.f, 0.f, 0.f, 0.f};
    if (row < 8) v = *(const float4*)(edw + (size_t)i * 4);
    ushort4 o = {f2bf(v.x), f2bf(v.y), f2bf(v.z), f2bf(v.w)};
    *(ushort4*)(edwb + (size_t)i * 4) = o;
}

// ---------------------------------------------------------------------------
// LayerNorm (ln2): one wave per row
__global__ __launch_bounds__(256) void ln_kernel(const float* __restrict__ src0,
                                                 const float* __restrict__ g,
                                                 const float* __restrict__ b,
                                                 unsigned short* __restrict__ dst0) {
    int lane = threadIdx.x & 63;
    int row  = blockIdx.x * 4 + (threadIdx.x >> 6);
    const float* p = src0 + (size_t)row * DMODEL + lane * 8;
    float4 v0 = *(const float4*)p;
    float4 v1 = *(const float4*)(p + 4);
    float s  = v0.x + v0.y + v0.z + v0.w + v1.x + v1.y + v1.z + v1.w;
    float ss = v0.x*v0.x + v0.y*v0.y + v0.z*v0.z + v0.w*v0.w
             + v1.x*v1.x + v1.y*v1.y + v1.z*v1.z + v1.w*v1.w;
    #pragma unroll
    for (int o = 32; o; o >>= 1) { s += __shfl_xor(s, o); ss += __shfl_xor(ss, o); }
    float m   = s * (1.0f / DMODEL);
    float var = ss * (1.0f / DMODEL) - m * m;
    float r   = rsqrtf(var + 1e-5f);
    float4 g0 = *(const float4*)(g + lane * 8);
    float4 g1 = *(const float4*)(g + lane * 8 + 4);
    float4 b0 = *(const float4*)(b + lane * 8);
    float4 b1 = *(const float4*)(b + lane * 8 + 4);
    unsigned short* q = dst0 + (size_t)row * DMODEL + lane * 8;
    ushort4 lo = {f2bf((v0.x-m)*r*g0.x+b0.x), f2bf((v0.y-m)*r*g0.y+b0.y),
                  f2bf((v0.z-m)*r*g0.z+b0.z), f2bf((v0.w-m)*r*g0.w+b0.w)};
    ushort4 hi = {f2bf((v1.x-m)*r*g1.x+b1.x), f2bf((v1.y-m)*r*g1.y+b1.y),
                  f2bf((v1.z-m)*r*g1.z+b1.z), f2bf((v1.w-m)*r*g1.w+b1.w)};
    *(ushort4*)q = lo;
    *(ushort4*)(q + 4) = hi;
}

// ---------------------------------------------------------------------------
// bf16 MFMA GEMM body (R4-proven): 64x64 tile, 4 waves, BK=64, 4-deep
// pipelined staging (counted vmcnt + raw barriers), XOR-swizzled LDS.
template<int ACT, int RES, int OBF>
__device__ __forceinline__ void gemm_body(const unsigned short* __restrict__ A,
        const unsigned short* __restrict__ W, const float* __restrict__ bv,
        const float* __restrict__ Rsd, void* __restrict__ Cv,
        int Nn, int K, int m0, int n0, short* As, short* Ws) {
    const int tid  = threadIdx.x;
    const int lane = tid & 63, w = tid >> 6;
    const int wr = w >> 1, wc = w & 1;
    const int s0 = tid, s1 = 256 + tid;
    const int r0 = s0 >> 3, c0 = ((s0 & 7) ^ (r0 & 7)) << 3;
    const int r1 = s1 >> 3, c1 = ((s1 & 7) ^ (r1 & 7)) << 3;
    const unsigned short* ag0 = A + (size_t)(m0 + r0) * K + c0;
    const unsigned short* ag1 = A + (size_t)(m0 + r1) * K + c1;
    const unsigned short* wg0 = W + (size_t)(n0 + r0) * K + c0;
    const unsigned short* wg1 = W + (size_t)(n0 + r1) * K + c1;

    f32x4 acc[2][2] = {};
    const int lc = lane & 15, lr = lane >> 4;
    const int KT = K >> 6;

    #pragma unroll
    for (int t = 0; t < 4; t++) {
        const int b = t * 4096, k0 = t << 6;
        gload_lds16(ag0 + k0, &As[b + s0 * 8]);
        gload_lds16(ag1 + k0, &As[b + s1 * 8]);
        gload_lds16(wg0 + k0, &Ws[b + s0 * 8]);
        gload_lds16(wg1 + k0, &Ws[b + s1 * 8]);
    }

    for (int t = 0; t < KT; t++) {
        int rem = KT - 1 - t; if (rem > 3) rem = 3;
        if (rem >= 3)      asm volatile("s_waitcnt vmcnt(12)" ::: "memory");
        else if (rem == 2) asm volatile("s_waitcnt vmcnt(8)"  ::: "memory");
        else if (rem == 1) asm volatile("s_waitcnt vmcnt(4)"  ::: "memory");
        else               asm volatile("s_waitcnt vmcnt(0)"  ::: "memory");
        __builtin_amdgcn_s_barrier();
        __builtin_amdgcn_sched_barrier(0);
        const int cur = (t & 3) * 4096;
        bf16x8 af[2][2], bfr[2][2];
        #pragma unroll
        for (int m = 0; m < 2; m++) {
            const int rra = wr * 32 + m * 16 + lc;
            #pragma unroll
            for (int kk = 0; kk < 2; kk++) {
                const int cc = (lr + kk * 4) ^ (rra & 7);
                af[m][kk] = *(const bf16x8*)&As[cur + rra * 64 + cc * 8];
            }
        }
        #pragma unroll
        for (int nn = 0; nn < 2; nn++) {
            const int rrb = wc * 32 + nn * 16 + lc;
            #pragma unroll
            for (int kk = 0; kk < 2; kk++) {
                const int cc = (lr + kk * 4) ^ (rrb & 7);
                bfr[nn][kk] = *(const bf16x8*)&Ws[cur + rrb * 64 + cc * 8];
            }
        }
        #pragma unroll
        for (int m = 0; m < 2; m++)
            #pragma unroll
            for (int nn = 0; nn < 2; nn++) {
                acc[m][nn] = __builtin_amdgcn_mfma_f32_16x16x32_bf16(af[m][0], bfr[nn][0], acc[m][nn], 0, 0, 0);
                acc[m][nn] = __builtin_amdgcn_mfma_f32_16x16x32_bf16(af[m][1], bfr[nn][1], acc[m][nn], 0, 0, 0);
            }
        if (t + 4 < KT) {
            __builtin_amdgcn_sched_barrier(0);
            __builtin_amdgcn_s_barrier();
            const int b = cur, k0 = (t + 4) << 6;
            gload_lds16(ag0 + k0, &As[b + s0 * 8]);
            gload_lds16(ag1 + k0, &As[b + s1 * 8]);
            gload_lds16(wg0 + k0, &Ws[b + s0 * 8]);
            gload_lds16(wg1 + k0, &Ws[b + s1 * 8]);
        }
    }

    #pragma unroll
    for (int nn = 0; nn < 2; nn++) {
        int gcol = n0 + wc * 32 + nn * 16 + lc;
        float bb = bv[gcol];
        #pragma unroll
        for (int m = 0; m < 2; m++) {
            #pragma unroll
            for (int r = 0; r < 4; r++) {
                int grow = m0 + wr * 32 + m * 16 + lr * 4 + r;
                float o = acc[m][nn][r] + bb;
                if (ACT) o = o / (1.0f + expf(-o));
                if (RES) o += Rsd[(size_t)grow * Nn + gcol];
                if (OBF) ((unsigned short*)Cv)[(size_t)grow * Nn + gcol] = f2bf(o);
                else     ((float*)Cv)[(size_t)grow * Nn + gcol] = o;
            }
        }
    }
}

template<int ACT, int RES, int OBF>
__global__ __launch_bounds__(256) void mfma_gemm(const unsigned short* __restrict__ A,
                                                 const unsigned short* __restrict__ W,
                                                 const float* __restrict__ bv,
                                                 const float* __restrict__ Rsd,
                                                 void* __restrict__ Cv, int Nn, int K) {
    __shared__ short As[4 * 4096];
    __shared__ short Ws[4 * 4096];
    gemm_body<ACT, RES, OBF>(A, W, bv, Rsd, Cv, Nn, K, blockIdx.y * 64, blockIdx.x * 64, As, Ws);
}

// merged q + kv projection -> bf16 outputs
__global__ __launch_bounds__(256) void qkv_gemm(const unsigned short* __restrict__ a_in,
                                                const unsigned short* __restrict__ a_mem,
                                                const unsigned short* __restrict__ qwb,
                                                const unsigned short* __restrict__ kvwb,
                                                const float* __restrict__ qbv,
                                                const float* __restrict__ kvbv,
                                                unsigned short* __restrict__ qbuf,
                                                unsigned short* __restrict__ kvbuf) {
    __shared__ short As[4 * 4096];
    __shared__ short Ws[4 * 4096];
    const int bx = blockIdx.x;
    const unsigned short* A; const unsigned short* W; const float* bv;
    unsigned short* C; int Nn, n0;
    if (bx < 8) { A = a_in;  W = qwb;  bv = qbv;  C = qbuf;  Nn = DMODEL;     n0 = bx * 64; }
    else        { A = a_mem; W = kvwb; bv = kvbv; C = kvbuf; Nn = 2 * DMODEL; n0 = (bx - 8) * 64; }
    gemm_body<0, 0, 1>(A, W, bv, nullptr, C, Nn, DMODEL, blockIdx.y * 64, n0, As, Ws);
}

// ---------------------------------------------------------------------------
// scores[n,h,i,j] = bf16( 0.125 * q_i.k_j + bf2f(biasb) )   (mask pre-folded)
__global__ __launch_bounds__(256) void scores_kernel(const unsigned short* __restrict__ q,
                                                     const unsigned short* __restrict__ kv,
                                                     const unsigned short* __restrict__ biasb,
                                                     unsigned short* __restrict__ S) {
    const int n = blockIdx.z, h = blockIdx.y;
    const int it = blockIdx.x / 12, jt = blockIdx.x % 12;
    __shared__ float Qs[64][32];
    __shared__ float Ks[64][32];
    const int tid = threadIdx.x;
    const int r = tid >> 3, c = (tid & 7) << 3;
    {
        const unsigned short* qp = q + ((size_t)(n * LSEQ + it * 32 + r)) * DMODEL + h * HD2 + c;
        ushort4 q0 = *(const ushort4*)qp;
        ushort4 q1 = *(const ushort4*)(qp + 4);
        Qs[c+0][r]=bf2f(q0.x); Qs[c+1][r]=bf2f(q0.y); Qs[c+2][r]=bf2f(q0.z); Qs[c+3][r]=bf2f(q0.w);
        Qs[c+4][r]=bf2f(q1.x); Qs[c+5][r]=bf2f(q1.y); Qs[c+6][r]=bf2f(q1.z); Qs[c+7][r]=bf2f(q1.w);
        const unsigned short* kp = kv + ((size_t)(n * LSEQ + jt * 32 + r)) * (2 * DMODEL) + h * HD2 + c;
        ushort4 k0 = *(const ushort4*)kp;
        ushort4 k1 = *(const ushort4*)(kp + 4);
        Ks[c+0][r]=bf2f(k0.x); Ks[c+1][r]=bf2f(k0.y); Ks[c+2][r]=bf2f(k0.z); Ks[c+3][r]=bf2f(k0.w);
        Ks[c+4][r]=bf2f(k1.x); Ks[c+5][r]=bf2f(k1.y); Ks[c+6][r]=bf2f(k1.z); Ks[c+7][r]=bf2f(k1.w);
    }
    __syncthreads();
    const int tx = tid & 15, ty = tid >> 4;
    float acc[2][2] = {{0.f,0.f},{0.f,0.f}};
    #pragma unroll
    for (int k = 0; k < 64; k++) {
        float2 a  = *(const float2*)&Qs[k][ty << 1];
        float2 b2 = *(const float2*)&Ks[k][tx << 1];
        acc[0][0] = fmaf(a.x, b2.x, acc[0][0]);
        acc[0][1] = fmaf(a.x, b2.y, acc[0][1]);
        acc[1][0] = fmaf(a.y, b2.x, acc[1][0]);
        acc[1][1] = fmaf(a.y, b2.y, acc[1][1]);
    }
    #pragma unroll
    for (int i2 = 0; i2 < 2; i2++) {
        int gi = it * 32 + (ty << 1) + i2;
        int gj = jt * 32 + (tx << 1);
        size_t idx = ((size_t)(n * 8 + h)) * LL2 + (size_t)gi * LSEQ + gj;
        ushort2 bb = *(const ushort2*)&biasb[idx];
        ushort2 so = {f2bf(acc[i2][0] * 0.125f + bf2f(bb.x)),
                      f2bf(acc[i2][1] * 0.125f + bf2f(bb.y))};
        *(ushort2*)&S[idx] = so;
    }
}

// ---------------------------------------------------------------------------
// row softmax over 384 cols (bf16 storage, f32 math); one wave per row
__global__ __launch_bounds__(256) void softmax_kernel(unsigned short* __restrict__ S) {
    int lane = threadIdx.x & 63;
    int row  = blockIdx.x * 4 + (threadIdx.x >> 6);
    unsigned short* p = S + (size_t)row * LSEQ;
    float v[6];
    #pragma unroll
    for (int cc = 0; cc < 6; cc++) v[cc] = bf2f(p[cc * 64 + lane]);
    float mx = v[0];
    #pragma unroll
    for (int cc = 1; cc < 6; cc++) mx = fmaxf(mx, v[cc]);
    #pragma unroll
    for (int o = 32; o; o >>= 1) mx = fmaxf(mx, __shfl_xor(mx, o));
    float sum = 0.f;
    #pragma unroll
    for (int cc = 0; cc < 6; cc++) { v[cc] = __expf(v[cc] - mx); sum += v[cc]; }
    #pragma unroll
    for (int o = 32; o; o >>= 1) sum += __shfl_xor(sum, o);
    float inv = 1.0f / sum;
    #pragma unroll
    for (int cc = 0; cc < 6; cc++) p[cc * 64 + lane] = f2bf(v[cc] * inv);
}

// ---------------------------------------------------------------------------
// attn_out = P @ V  -> bf16; P and V read as bf16, f32 accumulate
__global__ __launch_bounds__(256) void av_kernel(const unsigned short* __restrict__ S,
                                                 const unsigned short* __restrict__ kv,
                                                 const int* __restrict__ mask,
                                                 unsigned short* __restrict__ outb) {
    const int it = blockIdx.x, h = blockIdx.y, n = blockIdx.z;
    __shared__ float Ps[32][68];
    __shared__ float Vs[64][68];
    const int tid = threadIdx.x;
    const int lane = tid & 63;
    int pad = 1;
    for (int j = lane; j < LSEQ; j += 64) pad &= (mask[n * LSEQ + j] != 0) ? 1 : 0;
    unsigned long long bal = __ballot(pad != 0);
    const float zf = (bal == 0xFFFFFFFFFFFFFFFFull) ? 0.0f : 1.0f;
    const int tx = tid & 15, ty = tid >> 4;
    const int pr = tid >> 3, pc = (tid & 7) << 3;
    const int vr = tid >> 2, vc = (tid & 3) << 4;
    float acc0[4] = {0,0,0,0}, acc1[4] = {0,0,0,0};
    for (int j0 = 0; j0 < LSEQ; j0 += 64) {
        const unsigned short* sp = S + ((size_t)(n * 8 + h)) * LL2 + (size_t)(it * 32 + pr) * LSEQ + j0 + pc;
        ushort4 p0 = *(const ushort4*)sp;
        ushort4 p1 = *(const ushort4*)(sp + 4);
        Ps[pr][pc+0]=bf2f(p0.x); Ps[pr][pc+1]=bf2f(p0.y); Ps[pr][pc+2]=bf2f(p0.z); Ps[pr][pc+3]=bf2f(p0.w);
        Ps[pr][pc+4]=bf2f(p1.x); Ps[pr][pc+5]=bf2f(p1.y); Ps[pr][pc+6]=bf2f(p1.z); Ps[pr][pc+7]=bf2f(p1.w);
        const unsigned short* vp = kv + ((size_t)(n * LSEQ + j0 + vr)) * (2 * DMODEL)
                                      + DMODEL + h * HD2 + vc;
        #pragma unroll
        for (int u = 0; u < 4; u++) {
            ushort4 vv = *(const ushort4*)(vp + 4 * u);
            Vs[vr][vc + 4*u + 0] = bf2f(vv.x);
            Vs[vr][vc + 4*u + 1] = bf2f(vv.y);
            Vs[vr][vc + 4*u + 2] = bf2f(vv.z);
            Vs[vr][vc + 4*u + 3] = bf2f(vv.w);
        }
        __syncthreads();
        #pragma unroll
        for (int j = 0; j < 64; j++) {
            float pa  = Ps[ty][j];
            float pb2 = Ps[ty + 16][j];
            float4 vv = *(const float4*)&Vs[j][tx << 2];
            acc0[0] = fmaf(pa,  vv.x, acc0[0]);
            acc0[1] = fmaf(pa,  vv.y, acc0[1]);
            acc0[2] = fmaf(pa,  vv.z, acc0[2]);
            acc0[3] = fmaf(pa,  vv.w, acc0[3]);
            acc1[0] = fmaf(pb2, vv.x, acc1[0]);
            acc1[1] = fmaf(pb2, vv.y, acc1[1]);
            acc1[2] = fmaf(pb2, vv.z, acc1[2]);
            acc1[3] = fmaf(pb2, vv.w, acc1[3]);
        }
        __syncthreads();
    }
    int i0 = it * 32;
    ushort4 o0 = {f2bf(acc0[0]*zf), f2bf(acc0[1]*zf), f2bf(acc0[2]*zf), f2bf(acc0[3]*zf)};
    ushort4 o1 = {f2bf(acc1[0]*zf), f2bf(acc1[1]*zf), f2bf(acc1[2]*zf), f2bf(acc1[3]*zf)};
    *(ushort4*)&outb[((size_t)(n * LSEQ + i0 + ty)) * DMODEL + h * HD2 + (tx << 2)]      = o0;
    *(ushort4*)&outb[((size_t)(n * LSEQ + i0 + ty + 16)) * DMODEL + h * HD2 + (tx << 2)] = o1;
}

// ---------------------------------------------------------------------------
extern "C" void kernel_launch(void* const* d_in, const int* in_sizes, int n_in,
                              void* d_out, int out_size, void* d_ws, size_t ws_size,
                              hipStream_t stream) {
    const float* x    = (const float*)d_in[0];
    const float* mem  = (const float*)d_in[1];
    const float* pd   = (const float*)d_in[2];
    const int*   mask = (const int*)d_in[3];
    const float* qw   = (const float*)d_in[4];
    const float* qbv  = (const float*)d_in[5];
    const float* kvw  = (const float*)d_in[6];
    const float* kvbv = (const float*)d_in[7];
    const float* pw   = (const float*)d_in[8];
    const float* pbv  = (const float*)d_in[9];
    const float* edw  = (const float*)d_in[10];
    const float* edb  = (const float*)d_in[11];
    const float* ln1g = (const float*)d_in[12];
    const float* ln1b = (const float*)d_in[13];
    const float* ln2g = (const float*)d_in[14];
    const float* ln2b = (const float*)d_in[15];
    const float* w1   = (const float*)d_in[16];
    const float* b1   = (const float*)d_in[17];
    const float* w2   = (const float*)d_in[18];
    const float* b2   = (const float*)d_in[19];
    const float* w3   = (const float*)d_in[20];
    const float* b3   = (const float*)d_in[21];

    float* wsf = (float*)d_ws;
    unsigned short* biasb   = (unsigned short*)(wsf + 16);           // NB*NH*LL2 bf16
    unsigned short* scores16= biasb + (size_t)NB * NH * LL2;         // NB*NH*LL2 bf16
    unsigned short* qbuf16  = scores16 + (size_t)NB * NH * LL2;      // ROWS*DMODEL bf16
    unsigned short* kvbuf16 = qbuf16 + (size_t)ROWS * DMODEL;        // ROWS*2*DMODEL bf16
    float* x1buf = (float*)(kvbuf16 + (size_t)ROWS * 2 * DMODEL);    // ROWS*DMODEL f32
    unsigned short* a_in  = (unsigned short*)(x1buf + (size_t)ROWS * DMODEL);
    unsigned short* a_mem = a_in  + (size_t)ROWS * DMODEL;
    unsigned short* attno = a_mem + (size_t)ROWS * DMODEL;
    unsigned short* h0    = attno + (size_t)ROWS * DMODEL;
    unsigned short* h1    = h0    + (size_t)ROWS * DMODEL;
    unsigned short* h2    = h1    + (size_t)ROWS * DMLP;
    unsigned short* qwb   = h2    + (size_t)ROWS * DMLP;
    unsigned short* kvwb  = qwb   + (size_t)DMODEL * DMODEL;
    unsigned short* pwb   = kvwb  + (size_t)2 * DMODEL * DMODEL;
    unsigned short* w1b   = pwb   + (size_t)DMODEL * DMODEL;
    unsigned short* w2b   = w1b   + (size_t)DMLP * DMODEL;
    unsigned short* w3b   = w2b   + (size_t)DMLP * DMLP;
    unsigned short* edwb  = w3b   + (size_t)DMLP * DMODEL;           // 16*512 bf16

    float* outp = (float*)d_out;

    edw_cvt_kernel<<<8, 256, 0, stream>>>(edw, edwb);

    pre_bias_kernel<<<BIAS_BLOCKS + LN_BLOCKS + CVT_BLOCKS, 256, 0, stream>>>(
        pd, edwb, edb, mask, biasb,
        x, mem, ln1g, ln1b, a_in, a_mem,
        qw, kvw, pw, w1, w2, w3,
        qwb, kvwb, pwb, w1b, w2b, w3b);

    qkv_gemm<<<dim3(24, 12), 256, 0, stream>>>(a_in, a_mem, qwb, kvwb, qbv, kvbv,
                                               qbuf16, kvbuf16);

    scores_kernel<<<dim3(144, NH, NB), 256, 0, stream>>>(qbuf16, kvbuf16, biasb, scores16);
    softmax_kernel<<<(NB * NH * LSEQ) / 4, 256, 0, stream>>>(scores16);
    av_kernel<<<dim3(12, NH, NB), 256, 0, stream>>>(scores16, kvbuf16, mask, attno);

    mfma_gemm<0,1,0><<<dim3(8, 12), 256, 0, stream>>>(attno, pwb, pbv, x, x1buf, DMODEL, DMODEL);
    ln_kernel<<<ROWS / 4, 256, 0, stream>>>(x1buf, ln2g, ln2b, h0);
    mfma_gemm<1,0,1><<<dim3(32, 12), 256, 0, stream>>>(h0, w1b, b1, nullptr, h1, DMLP, DMODEL);
    mfma_gemm<1,0,1><<<dim3(32, 12), 256, 0, stream>>>(h1, w2b, b2, nullptr, h2, DMLP, DMLP);
    mfma_gemm<0,1,0><<<dim3(8, 12), 256, 0, stream>>>(h2, w3b, b3, x1buf, outp, DMODEL, DMLP);
}

// Round 12
// 234.059 us; speedup vs baseline: 1.1489x; 1.0067x over previous
//
#include <hip/hip_runtime.h>
#include <hip/hip_bf16.h>
#include <math.h>

// Problem constants
#define NB   2
#define LSEQ 384
#define DMODEL 512
#define NH   8
#define HD2  64
#define DMLP 2048
#define LL2  (LSEQ*LSEQ)          // 147456
#define ROWS (NB*LSEQ)            // 768

#define BIAS_BLOCKS (NB * LL2 / 64)   // 4608
#define LN_BLOCKS   384
#define CVT_BLOCKS  1024

using bf16x8 = __attribute__((ext_vector_type(8))) short;
using f32x4  = __attribute__((ext_vector_type(4))) float;

__device__ __forceinline__ unsigned short f2bf(float f) {
    union { __hip_bfloat16 h; unsigned short u; } cv;
    cv.h = __float2bfloat16(f);
    return cv.u;
}
__device__ __forceinline__ float bf2f(unsigned short u) {
    union { float f; unsigned int i; } c;
    c.i = ((unsigned int)u) << 16;
    return c.f;
}

__device__ __forceinline__ void gload_lds16(const void* g, void* l) {
    __builtin_amdgcn_global_load_lds(
        (const __attribute__((address_space(1))) void*)g,
        (__attribute__((address_space(3))) void*)l, 16, 0, 0);
}

// ---------------------------------------------------------------------------
// fused: bias MFMA (blocks 0..4607) + LN1 (4608..4991) + weight cvt (rest)
__global__ __launch_bounds__(256) void pre_bias_kernel(
        const float* __restrict__ pd, const unsigned short* __restrict__ edwb_in,
        const float* __restrict__ edb, const int* __restrict__ mask,
        unsigned short* __restrict__ biasb,
        const float* __restrict__ x, const float* __restrict__ mem,
        const float* __restrict__ ln1g, const float* __restrict__ ln1b,
        unsigned short* __restrict__ a_in, unsigned short* __restrict__ a_mem,
        const float* __restrict__ s0, const float* __restrict__ s1,
        const float* __restrict__ s2, const float* __restrict__ s3,
        const float* __restrict__ s4, const float* __restrict__ s5,
        unsigned short* __restrict__ d0, unsigned short* __restrict__ d1,
        unsigned short* __restrict__ d2, unsigned short* __restrict__ d3,
        unsigned short* __restrict__ d4, unsigned short* __restrict__ d5) {
    __shared__ float Asb[2][64 * 64];    // 2 x 16KB (bias path only)
    const int tid = threadIdx.x;

    if (blockIdx.x < BIAS_BLOCKS) {
        // ---------------- bias path (R8-proven drain version) ----------------
        const int lane = tid & 63, w = tid >> 6;
        const int T = blockIdx.x;
        const size_t row0 = (size_t)T * 64;
        const int n = T / 2304;
        const int rem64 = (T - n * 2304) * 64;
        const int i = rem64 / LSEQ, j0 = rem64 % LSEQ;

        int pad = 1;
        for (int j = lane; j < LSEQ; j += 64) pad &= (mask[n * LSEQ + j] != 0) ? 1 : 0;
        unsigned long long bal = __ballot(pad);
        const int ap = (bal == ~0ull) ? 1 : 0;

        int rr[4], sc[4];
        #pragma unroll
        for (int q = 0; q < 4; q++) {
            int s = q * 256 + tid;
            rr[q] = s >> 4;
            int cs = s & 15;
            sc[q] = (cs & 8) | ((cs & 7) ^ (rr[q] & 7));
        }

        const int c = lane & 15, g = lane >> 4;
        f32x4 acc = {};

        #pragma unroll
        for (int q = 0; q < 4; q++)
            gload_lds16(pd + (row0 + rr[q]) * DMODEL + sc[q] * 4, &Asb[0][(q * 256 + tid) * 4]);
        __syncthreads();

        for (int kc = 0; kc < 8; kc++) {
            if (kc < 7) {
                const int nb = (kc + 1) & 1;
                #pragma unroll
                for (int q = 0; q < 4; q++)
                    gload_lds16(pd + (row0 + rr[q]) * DMODEL + (kc + 1) * 64 + sc[q] * 4,
                                &Asb[nb][(q * 256 + tid) * 4]);
            }
            const float* Ab = &Asb[kc & 1][0];
            #pragma unroll
            for (int ks = 0; ks < 2; ks++) {
                const int ch0 = (8 * ks) | ((2 * g) ^ (c & 7));
                const int ch1 = (8 * ks) | ((2 * g + 1) ^ (c & 7));
                float4 a0 = *(const float4*)&Ab[(w * 16 + c) * 64 + ch0 * 4];
                float4 a1 = *(const float4*)&Ab[(w * 16 + c) * 64 + ch1 * 4];
                bf16x8 af;
                af[0] = (short)f2bf(a0.x); af[1] = (short)f2bf(a0.y);
                af[2] = (short)f2bf(a0.z); af[3] = (short)f2bf(a0.w);
                af[4] = (short)f2bf(a1.x); af[5] = (short)f2bf(a1.y);
                af[6] = (short)f2bf(a1.z); af[7] = (short)f2bf(a1.w);
                bf16x8 bfv = *(const bf16x8*)&edwb_in[c * 512 + kc * 64 + ks * 32 + g * 8];
                acc = __builtin_amdgcn_mfma_f32_16x16x32_bf16(af, bfv, acc, 0, 0, 0);
            }
            if (kc < 7) __syncthreads();
        }

        if (c < 8) {
            const float eb = edb[c];
            const int jj = j0 + w * 16 + g * 4;
            int4 mv = *(const int4*)&mask[n * LSEQ + jj];
            const float NEGINF = -__builtin_inff();
            ushort4 o;
            o.x = f2bf(acc[0] + eb + ((!ap && mv.x) ? NEGINF : 0.0f));
            o.y = f2bf(acc[1] + eb + ((!ap && mv.y) ? NEGINF : 0.0f));
            o.z = f2bf(acc[2] + eb + ((!ap && mv.z) ? NEGINF : 0.0f));
            o.w = f2bf(acc[3] + eb + ((!ap && mv.w) ? NEGINF : 0.0f));
            *(ushort4*)&biasb[(size_t)(n * 8 + c) * LL2 + (size_t)i * LSEQ + jj] = o;
        }
        return;
    }

    if (blockIdx.x < BIAS_BLOCKS + LN_BLOCKS) {
        // ---------------- LN1 path ----------------
        int lane = tid & 63;
        int row  = (blockIdx.x - BIAS_BLOCKS) * 4 + (tid >> 6);
        const float* src = (row < ROWS) ? x : mem;
        unsigned short* dst = (row < ROWS) ? a_in : a_mem;
        int r2 = (row < ROWS) ? row : row - ROWS;
        const float* p = src + (size_t)r2 * DMODEL + lane * 8;
        float4 v0 = *(const float4*)p;
        float4 v1 = *(const float4*)(p + 4);
        float s  = v0.x + v0.y + v0.z + v0.w + v1.x + v1.y + v1.z + v1.w;
        float ss = v0.x*v0.x + v0.y*v0.y + v0.z*v0.z + v0.w*v0.w
                 + v1.x*v1.x + v1.y*v1.y + v1.z*v1.z + v1.w*v1.w;
        #pragma unroll
        for (int o = 32; o; o >>= 1) { s += __shfl_xor(s, o); ss += __shfl_xor(ss, o); }
        float m   = s * (1.0f / DMODEL);
        float var = ss * (1.0f / DMODEL) - m * m;
        float r   = rsqrtf(var + 1e-5f);
        float4 g0 = *(const float4*)(ln1g + lane * 8);
        float4 g1 = *(const float4*)(ln1g + lane * 8 + 4);
        float4 b0 = *(const float4*)(ln1b + lane * 8);
        float4 b1 = *(const float4*)(ln1b + lane * 8 + 4);
        unsigned short* q = dst + (size_t)r2 * DMODEL + lane * 8;
        ushort4 lo = {f2bf((v0.x-m)*r*g0.x+b0.x), f2bf((v0.y-m)*r*g0.y+b0.y),
                      f2bf((v0.z-m)*r*g0.z+b0.z), f2bf((v0.w-m)*r*g0.w+b0.w)};
        ushort4 hi = {f2bf((v1.x-m)*r*g1.x+b1.x), f2bf((v1.y-m)*r*g1.y+b1.y),
                      f2bf((v1.z-m)*r*g1.z+b1.z), f2bf((v1.w-m)*r*g1.w+b1.w)};
        *(ushort4*)q = lo;
        *(ushort4*)(q + 4) = hi;
        return;
    }

    // ---------------- cvt path ----------------
    const int stride = CVT_BLOCKS * 256;
    const int t0 = (blockIdx.x - BIAS_BLOCKS - LN_BLOCKS) * 256 + tid;
    const float* srcs[6] = {s0, s1, s2, s3, s4, s5};
    unsigned short* dsts[6] = {d0, d1, d2, d3, d4, d5};
    const int nf4[6] = {DMODEL*DMODEL/4, 2*DMODEL*DMODEL/4, DMODEL*DMODEL/4,
                        DMLP*DMODEL/4, DMLP*DMLP/4, DMLP*DMODEL/4};
    #pragma unroll
    for (int a = 0; a < 6; a++) {
        const float* s = srcs[a];
        unsigned short* d = dsts[a];
        for (int i = t0; i < nf4[a]; i += stride) {
            float4 v = *(const float4*)(s + (size_t)i * 4);
            ushort4 o = {f2bf(v.x), f2bf(v.y), f2bf(v.z), f2bf(v.w)};
            *(ushort4*)(d + (size_t)i * 4) = o;
        }
    }
}

// ---------------------------------------------------------------------------
// edw pre-conversion with zero padding rows 8..15 (16x512 bf16 table)
__global__ void edw_cvt_kernel(const float* __restrict__ edw,
                               unsigned short* __restrict__ edwb) {
    int i = blockIdx.x * 256 + threadIdx.x;   // 8 blocks * 256 = 2048 = 16*512/4
    int row = i >> 7;
    float4 v = {0.f, 0.f, 0.f, 0.f};
    if (row < 8) v = *(const float4*)(edw + (size_t)i * 4);
    ushort4 o = {f2bf(v.x), f2bf(v.y), f2bf(v.z), f2bf(v.w)};
    *(ushort4*)(edwb + (size_t)i * 4) = o;
}

// ---------------------------------------------------------------------------
// LayerNorm (ln2): one wave per row
__global__ __launch_bounds__(256) void ln_kernel(const float* __restrict__ src0,
                                                 const float* __restrict__ g,
                                                 const float* __restrict__ b,
                                                 unsigned short* __restrict__ dst0) {
    int lane = threadIdx.x & 63;
    int row  = blockIdx.x * 4 + (threadIdx.x >> 6);
    const float* p = src0 + (size_t)row * DMODEL + lane * 8;
    float4 v0 = *(const float4*)p;
    float4 v1 = *(const float4*)(p + 4);
    float s  = v0.x + v0.y + v0.z + v0.w + v1.x + v1.y + v1.z + v1.w;
    float ss = v0.x*v0.x + v0.y*v0.y + v0.z*v0.z + v0.w*v0.w
             + v1.x*v1.x + v1.y*v1.y + v1.z*v1.z + v1.w*v1.w;
    #pragma unroll
    for (int o = 32; o; o >>= 1) { s += __shfl_xor(s, o); ss += __shfl_xor(ss, o); }
    float m   = s * (1.0f / DMODEL);
    float var = ss * (1.0f / DMODEL) - m * m;
    float r   = rsqrtf(var + 1e-5f);
    float4 g0 = *(const float4*)(g + lane * 8);
    float4 g1 = *(const float4*)(g + lane * 8 + 4);
    float4 b0 = *(const float4*)(b + lane * 8);
    float4 b1 = *(const float4*)(b + lane * 8 + 4);
    unsigned short* q = dst0 + (size_t)row * DMODEL + lane * 8;
    ushort4 lo = {f2bf((v0.x-m)*r*g0.x+b0.x), f2bf((v0.y-m)*r*g0.y+b0.y),
                  f2bf((v0.z-m)*r*g0.z+b0.z), f2bf((v0.w-m)*r*g0.w+b0.w)};
    ushort4 hi = {f2bf((v1.x-m)*r*g1.x+b1.x), f2bf((v1.y-m)*r*g1.y+b1.y),
                  f2bf((v1.z-m)*r*g1.z+b1.z), f2bf((v1.w-m)*r*g1.w+b1.w)};
    *(ushort4*)q = lo;
    *(ushort4*)(q + 4) = hi;
}

// ---------------------------------------------------------------------------
// bf16 MFMA GEMM body (R4-proven): 64x64 tile, 4 waves, BK=64, 4-deep
// pipelined staging (counted vmcnt + raw barriers), XOR-swizzled LDS.
template<int ACT, int RES, int OBF>
__device__ __forceinline__ void gemm_body(const unsigned short* __restrict__ A,
        const unsigned short* __restrict__ W, const float* __restrict__ bv,
        const float* __restrict__ Rsd, void* __restrict__ Cv,
        int Nn, int K, int m0, int n0, short* As, short* Ws) {
    const int tid  = threadIdx.x;
    const int lane = tid & 63, w = tid >> 6;
    const int wr = w >> 1, wc = w & 1;
    const int s0 = tid, s1 = 256 + tid;
    const int r0 = s0 >> 3, c0 = ((s0 & 7) ^ (r0 & 7)) << 3;
    const int r1 = s1 >> 3, c1 = ((s1 & 7) ^ (r1 & 7)) << 3;
    const unsigned short* ag0 = A + (size_t)(m0 + r0) * K + c0;
    const unsigned short* ag1 = A + (size_t)(m0 + r1) * K + c1;
    const unsigned short* wg0 = W + (size_t)(n0 + r0) * K + c0;
    const unsigned short* wg1 = W + (size_t)(n0 + r1) * K + c1;

    f32x4 acc[2][2] = {};
    const int lc = lane & 15, lr = lane >> 4;
    const int KT = K >> 6;

    #pragma unroll
    for (int t = 0; t < 4; t++) {
        const int b = t * 4096, k0 = t << 6;
        gload_lds16(ag0 + k0, &As[b + s0 * 8]);
        gload_lds16(ag1 + k0, &As[b + s1 * 8]);
        gload_lds16(wg0 + k0, &Ws[b + s0 * 8]);
        gload_lds16(wg1 + k0, &Ws[b + s1 * 8]);
    }

    for (int t = 0; t < KT; t++) {
        int rem = KT - 1 - t; if (rem > 3) rem = 3;
        if (rem >= 3)      asm volatile("s_waitcnt vmcnt(12)" ::: "memory");
        else if (rem == 2) asm volatile("s_waitcnt vmcnt(8)"  ::: "memory");
        else if (rem == 1) asm volatile("s_waitcnt vmcnt(4)"  ::: "memory");
        else               asm volatile("s_waitcnt vmcnt(0)"  ::: "memory");
        __builtin_amdgcn_s_barrier();
        __builtin_amdgcn_sched_barrier(0);
        const int cur = (t & 3) * 4096;
        bf16x8 af[2][2], bfr[2][2];
        #pragma unroll
        for (int m = 0; m < 2; m++) {
            const int rra = wr * 32 + m * 16 + lc;
            #pragma unroll
            for (int kk = 0; kk < 2; kk++) {
                const int cc = (lr + kk * 4) ^ (rra & 7);
                af[m][kk] = *(const bf16x8*)&As[cur + rra * 64 + cc * 8];
            }
        }
        #pragma unroll
        for (int nn = 0; nn < 2; nn++) {
            const int rrb = wc * 32 + nn * 16 + lc;
            #pragma unroll
            for (int kk = 0; kk < 2; kk++) {
                const int cc = (lr + kk * 4) ^ (rrb & 7);
                bfr[nn][kk] = *(const bf16x8*)&Ws[cur + rrb * 64 + cc * 8];
            }
        }
        #pragma unroll
        for (int m = 0; m < 2; m++)
            #pragma unroll
            for (int nn = 0; nn < 2; nn++) {
                acc[m][nn] = __builtin_amdgcn_mfma_f32_16x16x32_bf16(af[m][0], bfr[nn][0], acc[m][nn], 0, 0, 0);
                acc[m][nn] = __builtin_amdgcn_mfma_f32_16x16x32_bf16(af[m][1], bfr[nn][1], acc[m][nn], 0, 0, 0);
            }
        if (t + 4 < KT) {
            __builtin_amdgcn_sched_barrier(0);
            __builtin_amdgcn_s_barrier();
            const int b = cur, k0 = (t + 4) << 6;
            gload_lds16(ag0 + k0, &As[b + s0 * 8]);
            gload_lds16(ag1 + k0, &As[b + s1 * 8]);
            gload_lds16(wg0 + k0, &Ws[b + s0 * 8]);
            gload_lds16(wg1 + k0, &Ws[b + s1 * 8]);
        }
    }

    #pragma unroll
    for (int nn = 0; nn < 2; nn++) {
        int gcol = n0 + wc * 32 + nn * 16 + lc;
        float bb = bv[gcol];
        #pragma unroll
        for (int m = 0; m < 2; m++) {
            #pragma unroll
            for (int r = 0; r < 4; r++) {
                int grow = m0 + wr * 32 + m * 16 + lr * 4 + r;
                float o = acc[m][nn][r] + bb;
                if (ACT) o = o / (1.0f + expf(-o));
                if (RES) o += Rsd[(size_t)grow * Nn + gcol];
                if (OBF) ((unsigned short*)Cv)[(size_t)grow * Nn + gcol] = f2bf(o);
                else     ((float*)Cv)[(size_t)grow * Nn + gcol] = o;
            }
        }
    }
}

template<int ACT, int RES, int OBF>
__global__ __launch_bounds__(256) void mfma_gemm(const unsigned short* __restrict__ A,
                                                 const unsigned short* __restrict__ W,
                                                 const float* __restrict__ bv,
                                                 const float* __restrict__ Rsd,
                                                 void* __restrict__ Cv, int Nn, int K) {
    __shared__ short As[4 * 4096];
    __shared__ short Ws[4 * 4096];
    gemm_body<ACT, RES, OBF>(A, W, bv, Rsd, Cv, Nn, K, blockIdx.y * 64, blockIdx.x * 64, As, Ws);
}

// merged q + kv projection -> bf16 outputs
__global__ __launch_bounds__(256) void qkv_gemm(const unsigned short* __restrict__ a_in,
                                                const unsigned short* __restrict__ a_mem,
                                                const unsigned short* __restrict__ qwb,
                                                const unsigned short* __restrict__ kvwb,
                                                const float* __restrict__ qbv,
                                                const float* __restrict__ kvbv,
                                                unsigned short* __restrict__ qbuf,
                                                unsigned short* __restrict__ kvbuf) {
    __shared__ short As[4 * 4096];
    __shared__ short Ws[4 * 4096];
    const int bx = blockIdx.x;
    const unsigned short* A; const unsigned short* W; const float* bv;
    unsigned short* C; int Nn, n0;
    if (bx < 8) { A = a_in;  W = qwb;  bv = qbv;  C = qbuf;  Nn = DMODEL;     n0 = bx * 64; }
    else        { A = a_mem; W = kvwb; bv = kvbv; C = kvbuf; Nn = 2 * DMODEL; n0 = (bx - 8) * 64; }
    gemm_body<0, 0, 1>(A, W, bv, nullptr, C, Nn, DMODEL, blockIdx.y * 64, n0, As, Ws);
}

// ---------------------------------------------------------------------------
// scores[n,h,i,j] = bf16( 0.125 * q_i.k_j + bf2f(biasb) )   (mask pre-folded)
__global__ __launch_bounds__(256) void scores_kernel(const unsigned short* __restrict__ q,
                                                     const unsigned short* __restrict__ kv,
                                                     const unsigned short* __restrict__ biasb,
                                                     unsigned short* __restrict__ S) {
    const int n = blockIdx.z, h = blockIdx.y;
    const int it = blockIdx.x / 12, jt = blockIdx.x % 12;
    __shared__ float Qs[64][32];
    __shared__ float Ks[64][32];
    const int tid = threadIdx.x;
    const int r = tid >> 3, c = (tid & 7) << 3;
    {
        const unsigned short* qp = q + ((size_t)(n * LSEQ + it * 32 + r)) * DMODEL + h * HD2 + c;
        ushort4 q0 = *(const ushort4*)qp;
        ushort4 q1 = *(const ushort4*)(qp + 4);
        Qs[c+0][r]=bf2f(q0.x); Qs[c+1][r]=bf2f(q0.y); Qs[c+2][r]=bf2f(q0.z); Qs[c+3][r]=bf2f(q0.w);
        Qs[c+4][r]=bf2f(q1.x); Qs[c+5][r]=bf2f(q1.y); Qs[c+6][r]=bf2f(q1.z); Qs[c+7][r]=bf2f(q1.w);
        const unsigned short* kp = kv + ((size_t)(n * LSEQ + jt * 32 + r)) * (2 * DMODEL) + h * HD2 + c;
        ushort4 k0 = *(const ushort4*)kp;
        ushort4 k1 = *(const ushort4*)(kp + 4);
        Ks[c+0][r]=bf2f(k0.x); Ks[c+1][r]=bf2f(k0.y); Ks[c+2][r]=bf2f(k0.z); Ks[c+3][r]=bf2f(k0.w);
        Ks[c+4][r]=bf2f(k1.x); Ks[c+5][r]=bf2f(k1.y); Ks[c+6][r]=bf2f(k1.z); Ks[c+7][r]=bf2f(k1.w);
    }
    __syncthreads();
    const int tx = tid & 15, ty = tid >> 4;
    float acc[2][2] = {{0.f,0.f},{0.f,0.f}};
    #pragma unroll
    for (int k = 0; k < 64; k++) {
        float2 a  = *(const float2*)&Qs[k][ty << 1];
        float2 b2 = *(const float2*)&Ks[k][tx << 1];
        acc[0][0] = fmaf(a.x, b2.x, acc[0][0]);
        acc[0][1] = fmaf(a.x, b2.y, acc[0][1]);
        acc[1][0] = fmaf(a.y, b2.x, acc[1][0]);
        acc[1][1] = fmaf(a.y, b2.y, acc[1][1]);
    }
    #pragma unroll
    for (int i2 = 0; i2 < 2; i2++) {
        int gi = it * 32 + (ty << 1) + i2;
        int gj = jt * 32 + (tx << 1);
        size_t idx = ((size_t)(n * 8 + h)) * LL2 + (size_t)gi * LSEQ + gj;
        ushort2 bb = *(const ushort2*)&biasb[idx];
        ushort2 so = {f2bf(acc[i2][0] * 0.125f + bf2f(bb.x)),
                      f2bf(acc[i2][1] * 0.125f + bf2f(bb.y))};
        *(ushort2*)&S[idx] = so;
    }
}

// ---------------------------------------------------------------------------
// fused softmax + AV: stage full 32x384 S block in LDS (bf16), in-register
// row softmax (8 threads/row x 48 cols), write P back to LDS, then the
// R11-proven PV loop reading P from LDS. One kernel instead of two.
__global__ __launch_bounds__(256) void av_sm_kernel(const unsigned short* __restrict__ S,
                                                    const unsigned short* __restrict__ kv,
                                                    const int* __restrict__ mask,
                                                    unsigned short* __restrict__ outb) {
    __shared__ unsigned short Psb[32][392];   // 24.5 KB bf16, padded stride
    __shared__ float Vs[64][68];              // 17.4 KB
    const int it = blockIdx.x, h = blockIdx.y, n = blockIdx.z;
    const int tid = threadIdx.x;
    const int lane = tid & 63;
    int pad = 1;
    for (int j = lane; j < LSEQ; j += 64) pad &= (mask[n * LSEQ + j] != 0) ? 1 : 0;
    unsigned long long bal = __ballot(pad != 0);
    const float zf = (bal == 0xFFFFFFFFFFFFFFFFull) ? 0.0f : 1.0f;

    // stage full S row-block: 32 x 384 bf16 = 6 x 16B chunks per thread
    const unsigned short* sb = S + ((size_t)(n * 8 + h)) * LL2 + (size_t)(it * 32) * LSEQ;
    #pragma unroll
    for (int q = 0; q < 6; q++) {
        int s = q * 256 + tid;
        int rw = s / 48, ch = s % 48;     // 48 chunks of 8 bf16 per row
        ushort4 a = *(const ushort4*)&sb[(size_t)rw * LSEQ + ch * 8];
        ushort4 b = *(const ushort4*)&sb[(size_t)rw * LSEQ + ch * 8 + 4];
        *(ushort4*)&Psb[rw][ch * 8]     = a;
        *(ushort4*)&Psb[rw][ch * 8 + 4] = b;
    }
    __syncthreads();

    // row softmax: row r = tid>>3, sub-slice sub = tid&7 covers 48 cols
    {
        const int r = tid >> 3, sub = tid & 7;
        float vv[48];
        float mx = -3.0e38f;
        #pragma unroll
        for (int u = 0; u < 48; u++) {
            vv[u] = bf2f(Psb[r][sub * 48 + u]);
            mx = fmaxf(mx, vv[u]);
        }
        #pragma unroll
        for (int o = 4; o; o >>= 1) mx = fmaxf(mx, __shfl_xor(mx, o));
        float sum = 0.f;
        #pragma unroll
        for (int u = 0; u < 48; u++) { vv[u] = __expf(vv[u] - mx); sum += vv[u]; }
        #pragma unroll
        for (int o = 4; o; o >>= 1) sum += __shfl_xor(sum, o);
        float inv = 1.0f / sum;
        #pragma unroll
        for (int u = 0; u < 48; u++) Psb[r][sub * 48 + u] = f2bf(vv[u] * inv);
    }
    __syncthreads();

    const int tx = tid & 15, ty = tid >> 4;
    const int vr = tid >> 2, vc = (tid & 3) << 4;
    float acc0[4] = {0,0,0,0}, acc1[4] = {0,0,0,0};
    for (int j0 = 0; j0 < LSEQ; j0 += 64) {
        const unsigned short* vp = kv + ((size_t)(n * LSEQ + j0 + vr)) * (2 * DMODEL)
                                      + DMODEL + h * HD2 + vc;
        #pragma unroll
        for (int u = 0; u < 4; u++) {
            ushort4 vvv = *(const ushort4*)(vp + 4 * u);
            Vs[vr][vc + 4*u + 0] = bf2f(vvv.x);
            Vs[vr][vc + 4*u + 1] = bf2f(vvv.y);
            Vs[vr][vc + 4*u + 2] = bf2f(vvv.z);
            Vs[vr][vc + 4*u + 3] = bf2f(vvv.w);
        }
        __syncthreads();
        #pragma unroll
        for (int j = 0; j < 64; j++) {
            float pa  = bf2f(Psb[ty][j0 + j]);
            float pb2 = bf2f(Psb[ty + 16][j0 + j]);
            float4 vv = *(const float4*)&Vs[j][tx << 2];
            acc0[0] = fmaf(pa,  vv.x, acc0[0]);
            acc0[1] = fmaf(pa,  vv.y, acc0[1]);
            acc0[2] = fmaf(pa,  vv.z, acc0[2]);
            acc0[3] = fmaf(pa,  vv.w, acc0[3]);
            acc1[0] = fmaf(pb2, vv.x, acc1[0]);
            acc1[1] = fmaf(pb2, vv.y, acc1[1]);
            acc1[2] = fmaf(pb2, vv.z, acc1[2]);
            acc1[3] = fmaf(pb2, vv.w, acc1[3]);
        }
        __syncthreads();
    }
    int i0 = it * 32;
    ushort4 o0 = {f2bf(acc0[0]*zf), f2bf(acc0[1]*zf), f2bf(acc0[2]*zf), f2bf(acc0[3]*zf)};
    ushort4 o1 = {f2bf(acc1[0]*zf), f2bf(acc1[1]*zf), f2bf(acc1[2]*zf), f2bf(acc1[3]*zf)};
    *(ushort4*)&outb[((size_t)(n * LSEQ + i0 + ty)) * DMODEL + h * HD2 + (tx << 2)]      = o0;
    *(ushort4*)&outb[((size_t)(n * LSEQ + i0 + ty + 16)) * DMODEL + h * HD2 + (tx << 2)] = o1;
}

// ---------------------------------------------------------------------------
extern "C" void kernel_launch(void* const* d_in, const int* in_sizes, int n_in,
                              void* d_out, int out_size, void* d_ws, size_t ws_size,
                              hipStream_t stream) {
    const float* x    = (const float*)d_in[0];
    const float* mem  = (const float*)d_in[1];
    const float* pd   = (const float*)d_in[2];
    const int*   mask = (const int*)d_in[3];
    const float* qw   = (const float*)d_in[4];
    const float* qbv  = (const float*)d_in[5];
    const float* kvw  = (const float*)d_in[6];
    const float* kvbv = (const float*)d_in[7];
    const float* pw   = (const float*)d_in[8];
    const float* pbv  = (const float*)d_in[9];
    const float* edw  = (const float*)d_in[10];
    const float* edb  = (const float*)d_in[11];
    const float* ln1g = (const float*)d_in[12];
    const float* ln1b = (const float*)d_in[13];
    const float* ln2g = (const float*)d_in[14];
    const float* ln2b = (const float*)d_in[15];
    const float* w1   = (const float*)d_in[16];
    const float* b1   = (const float*)d_in[17];
    const float* w2   = (const float*)d_in[18];
    const float* b2   = (const float*)d_in[19];
    const float* w3   = (const float*)d_in[20];
    const float* b3   = (const float*)d_in[21];

    float* wsf = (float*)d_ws;
    unsigned short* biasb   = (unsigned short*)(wsf + 16);           // NB*NH*LL2 bf16
    unsigned short* scores16= biasb + (size_t)NB * NH * LL2;         // NB*NH*LL2 bf16
    unsigned short* qbuf16  = scores16 + (size_t)NB * NH * LL2;      // ROWS*DMODEL bf16
    unsigned short* kvbuf16 = qbuf16 + (size_t)ROWS * DMODEL;        // ROWS*2*DMODEL bf16
    float* x1buf = (float*)(kvbuf16 + (size_t)ROWS * 2 * DMODEL);    // ROWS*DMODEL f32
    unsigned short* a_in  = (unsigned short*)(x1buf + (size_t)ROWS * DMODEL);
    unsigned short* a_mem = a_in  + (size_t)ROWS * DMODEL;
    unsigned short* attno = a_mem + (size_t)ROWS * DMODEL;
    unsigned short* h0    = attno + (size_t)ROWS * DMODEL;
    unsigned short* h1    = h0    + (size_t)ROWS * DMODEL;
    unsigned short* h2    = h1    + (size_t)ROWS * DMLP;
    unsigned short* qwb   = h2    + (size_t)ROWS * DMLP;
    unsigned short* kvwb  = qwb   + (size_t)DMODEL * DMODEL;
    unsigned short* pwb   = kvwb  + (size_t)2 * DMODEL * DMODEL;
    unsigned short* w1b   = pwb   + (size_t)DMODEL * DMODEL;
    unsigned short* w2b   = w1b   + (size_t)DMLP * DMODEL;
    unsigned short* w3b   = w2b   + (size_t)DMLP * DMLP;
    unsigned short* edwb  = w3b   + (size_t)DMLP * DMODEL;           // 16*512 bf16

    float* outp = (float*)d_out;

    edw_cvt_kernel<<<8, 256, 0, stream>>>(edw, edwb);

    pre_bias_kernel<<<BIAS_BLOCKS + LN_BLOCKS + CVT_BLOCKS, 256, 0, stream>>>(
        pd, edwb, edb, mask, biasb,
        x, mem, ln1g, ln1b, a_in, a_mem,
        qw, kvw, pw, w1, w2, w3,
        qwb, kvwb, pwb, w1b, w2b, w3b);

    qkv_gemm<<<dim3(24, 12), 256, 0, stream>>>(a_in, a_mem, qwb, kvwb, qbv, kvbv,
                                               qbuf16, kvbuf16);

    scores_kernel<<<dim3(144, NH, NB), 256, 0, stream>>>(qbuf16, kvbuf16, biasb, scores16);
    av_sm_kernel<<<dim3(12, NH, NB), 256, 0, stream>>>(scores16, kvbuf16, mask, attno);

    mfma_gemm<0,1,0><<<dim3(8, 12), 256, 0, stream>>>(attno, pwb, pbv, x, x1buf, DMODEL, DMODEL);
    ln_kernel<<<ROWS / 4, 256, 0, stream>>>(x1buf, ln2g, ln2b, h0);
    mfma_gemm<1,0,1><<<dim3(32, 12), 256, 0, stream>>>(h0, w1b, b1, nullptr, h1, DMLP, DMODEL);
    mfma_gemm<1,0,1><<<dim3(32, 12), 256, 0, stream>>>(h1, w2b, b2, nullptr, h2, DMLP, DMLP);
    mfma_gemm<0,1,0><<<dim3(8, 12), 256, 0, stream>>>(h2, w3b, b3, x1buf, outp, DMODEL, DMLP);
}